// Round 5
// baseline (684.524 us; speedup 1.0000x reference)
//
#include <hip/hip_runtime.h>
#include <hip/hip_bf16.h>
#include <cstddef>
#include <cstdint>

typedef __hip_bfloat16 hbf;
typedef __bf16 bf16x8 __attribute__((ext_vector_type(8)));
typedef __bf16 bf16x4 __attribute__((ext_vector_type(4)));
typedef float f32x4 __attribute__((ext_vector_type(4)));

#define GLDS(gp, lp) __builtin_amdgcn_global_load_lds( \
    (const __attribute__((address_space(1))) void*)(gp), \
    (__attribute__((address_space(3))) void*)(lp), 16, 0, 0)

// bn: y = x*s + t, s = g*rsqrt(v+eps), t = b - m*s
__device__ __forceinline__ void bn_coef(const float* __restrict__ p, int C, int c,
                                        float& s, float& t) {
    float g = p[c];
    float b = p[C + c];
    float m = p[2 * C + c];
    float v = p[3 * C + c];
    s = g * rsqrtf(v + 1e-5f);
    t = b - m * s;
}

// ---------------- zero-fill (dwords) --------------------------------------------
__global__ void k_fill0(uint32_t* __restrict__ p, int n) {
    int i = blockIdx.x * blockDim.x + threadIdx.x;
    if (i < n) p[i] = 0u;
}

// ---------------- c1 fp32 [2,256,96,96] -> c1t bf16 [n][100*100][256], pad=2 ----
__global__ __launch_bounds__(256) void k_c1trans(const float* __restrict__ x,
                                                 hbf* __restrict__ c1t) {
    __shared__ float tbuf[32][33];
    const int p0 = blockIdx.x * 32, c0 = blockIdx.y * 32, n = blockIdx.z;
    const int tx = threadIdx.x, ty = threadIdx.y;
#pragma unroll
    for (int i = 0; i < 4; ++i) {
        int ci = c0 + ty * 4 + i;
        tbuf[ty * 4 + i][tx] = x[((size_t)(n * 256 + ci)) * 9216 + p0 + tx];
    }
    __syncthreads();
#pragma unroll
    for (int i = 0; i < 4; ++i) {
        int p = p0 + ty * 4 + i;
        int pp = (p / 96 + 2) * 100 + (p % 96) + 2;
        c1t[((size_t)(n * 10000 + pp)) * 256 + c0 + tx] = __float2bfloat16(tbuf[tx][ty * 4 + i]);
    }
}

// ---------------- both small conv weights -> [tap][64][CI] bf16, one launch -----
__global__ __launch_bounds__(256) void k_wsmall(const float* __restrict__ w1,
                                                hbf* __restrict__ wt1,
                                                const float* __restrict__ w2,
                                                hbf* __restrict__ wt2) {
    int b = blockIdx.x;
    if (b < 64) {           // w_r1: [64][256][3][3]
        int idx = b * 256 + threadIdx.x;
        int co = idx >> 8, ci = idx & 255;
        const float* s = w1 + ((size_t)(co * 256 + ci)) * 9;
#pragma unroll
        for (int tap = 0; tap < 9; ++tap)
            wt1[((size_t)(tap * 64 + co)) * 256 + ci] = __float2bfloat16(s[tap]);
    } else {                // w_r2: [64][64][3][3]
        int idx = (b - 64) * 256 + threadIdx.x;
        int co = idx >> 6, ci = idx & 63;
        const float* s = w2 + ((size_t)(co * 64 + ci)) * 9;
#pragma unroll
        for (int tap = 0; tap < 9; ++tap)
            wt2[((size_t)(tap * 64 + co)) * 64 + ci] = __float2bfloat16(s[tap]);
    }
}

// ---------------- dilated 3x3 conv (d=2) MFMA, tap-fused, pipelined dbuf --------
template <int CI>
__global__ __launch_bounds__(256) void k_dconv_mfma(const hbf* __restrict__ wt,
                                                    const hbf* __restrict__ it,
                                                    float* __restrict__ accout) {
    __shared__ hbf As[2][3][64 * 32];   // per-tap weights [64 co][32 k]
    __shared__ hbf Bs[2][72 * 32];      // union of pixel rows (tap col-shifts -2,0,+2)
    const int tid = threadIdx.x;
    const int l = tid & 63, w = tid >> 6;
    const int P0 = blockIdx.x * 64;
    const int g  = blockIdx.y;                 // tap row (dy = 2g-2)
    const int r0 = tid >> 2;
    const int swzk = ((tid & 3) ^ ((r0 >> 1) & 3)) * 8;

    const int n_i = P0 / 9216;
    const int pl0 = P0 - n_i * 9216;
    const int pp0 = (pl0 / 96 + 2) * 100 + (pl0 % 96) + 2;
    const ptrdiff_t browbase = (ptrdiff_t)n_i * 10000 + pp0 + (g - 1) * 200 - 2;

    const int wn = w * 16;
    const int pl_lane = pl0 + wn + (l & 15);
    const int jb = ((pl_lane / 96 + 2) * 100 + (pl_lane % 96) + 2) - pp0;  // 0..67
    const int slotA = ((l >> 4) ^ ((l >> 1) & 3)) * 8;

    f32x4 acc[4];
#pragma unroll
    for (int i = 0; i < 4; ++i) acc[i] = {0.f, 0.f, 0.f, 0.f};

    const hbf* gA = wt + ((size_t)(g * 192 + r0)) * CI + swzk;
    const hbf* gB = it + (size_t)(browbase + r0) * CI + swzk;

#define STAGE_D(buf, k0) do {                                                  \
        hbf* ldsA_ = &As[buf][0][0] + w * 512;                                 \
        hbf* ldsB_ = &Bs[buf][0] + w * 512;                                    \
        _Pragma("unroll")                                                      \
        for (int t_ = 0; t_ < 3; ++t_)                                         \
            GLDS(gA + (size_t)t_ * 64 * CI + (k0), ldsA_ + t_ * 2048);         \
        GLDS(gB + (k0), ldsB_);                                                \
        if (tid < 32)                                                          \
            GLDS(gB + (size_t)64 * CI + (k0), &Bs[buf][0] + 2048);             \
    } while (0)

    STAGE_D(0, 0);
    int cur = 0;
#pragma unroll 2
    for (int k0 = 0; k0 < CI; k0 += 32) {
        __syncthreads();   // drains prev stage (issued one compute phase ago)
        if (k0 + 32 < CI) STAGE_D(cur ^ 1, k0 + 32);
#pragma unroll
        for (int t = 0; t < 3; ++t) {
            const int brow = jb + 2 * t;
            bf16x8 bfr = *(const bf16x8*)(&Bs[cur][0] + brow * 32 + (((l >> 4) ^ ((brow >> 1) & 3)) * 8));
#pragma unroll
            for (int ti = 0; ti < 4; ++ti) {
                bf16x8 af = *(const bf16x8*)(&As[cur][t][(ti * 16 + (l & 15)) * 32 + slotA]);
                acc[ti] = __builtin_amdgcn_mfma_f32_16x16x32_bf16(af, bfr, acc[ti], 0, 0, 0);
            }
        }
        cur ^= 1;
    }
#undef STAGE_D

    const int px = P0 + wn + (l & 15);
    const int n2 = px / 9216, pl2 = px % 9216;
#pragma unroll
    for (int ti = 0; ti < 4; ++ti) {
        const int mrow = ti * 16 + (l >> 4) * 4;
        float* dst = accout + ((size_t)(n2 * 64 + mrow)) * 9216 + pl2;
#pragma unroll
        for (int r = 0; r < 4; ++r)
            atomicAdd(dst + (size_t)r * 9216, acc[ti][r]);
    }
}

// ---------------- ep_r1: BN+ReLU(r1acc) -> r1t bf16 padded-transposed -----------
// 288 blocks x 4-way channel split (was 72 blocks doing 64ch serially).
__global__ __launch_bounds__(256) void k_ep_r1(const float* __restrict__ acc,
                                               const float* __restrict__ bnp,
                                               hbf* __restrict__ r1t) {
    const int q = threadIdx.x >> 6;         // channel quarter
    const int ln = threadIdx.x & 63;
    const int pi = blockIdx.x * 64 + ln;    // 0..18431
    const int n = pi / 9216, pl = pi % 9216;
    const int pp = (pl / 96 + 2) * 100 + (pl % 96) + 2;
    hbf* dst = r1t + ((size_t)(n * 10000 + pp)) * 64 + q * 16;
    const float* src = acc + (size_t)(n * 64 + q * 16) * 9216 + pl;
#pragma unroll
    for (int i = 0; i < 16; ++i) {
        float s, t; bn_coef(bnp, 64, q * 16 + i, s, t);
        dst[i] = __float2bfloat16(fmaxf(fmaf(src[(size_t)i * 9216], s, t), 0.f));
    }
}

// ---------------- 1x1 conv on c2 (512->64), ci split 4-ways, atomic -------------
__global__ __launch_bounds__(192) void k_conv1x1_c2(const float* __restrict__ c2,
                                                    const float* __restrict__ w,
                                                    float* __restrict__ outacc) {
    const int x = threadIdx.x;
    const int y = blockIdx.y * 4 + threadIdx.y;
    const int n = blockIdx.z >> 2;
    const int ci0 = (blockIdx.z & 3) * 128;
    const int cg = blockIdx.x;
    const int p = y * 48 + x;
    float acc[8];
#pragma unroll
    for (int j = 0; j < 8; ++j) acc[j] = 0.f;
    for (int ci = ci0; ci < ci0 + 128; ++ci) {
        float iv = c2[(size_t)(n * 512 + ci) * 2304 + p];
#pragma unroll
        for (int j = 0; j < 8; ++j)
            acc[j] = fmaf(iv, w[(size_t)(cg * 8 + j) * 512 + ci], acc[j]);
    }
#pragma unroll
    for (int j = 0; j < 8; ++j)
        atomicAdd(&outacc[(size_t)(n * 64 + cg * 8 + j) * 2304 + p], acc[j]);
}

// ---------------- bilinear 48->96 (align_corners), optional BN+ReLU -------------
__global__ void k_up96(const float* __restrict__ src, float* __restrict__ dst,
                       int C, const float* __restrict__ bnp) {
    int idx = blockIdx.x * blockDim.x + threadIdx.x;  // 2*C*9216
    int p = idx % 9216;
    int nc = idx / 9216;
    int c = nc % C;
    int y = p / 96, x = p % 96;
    int yn = y * 47, xn = x * 47;
    int y0 = yn / 95, x0 = xn / 95;
    float wy = (float)(yn - y0 * 95) * (1.f / 95.f);
    float wx = (float)(xn - x0 * 95) * (1.f / 95.f);
    int y1 = min(y0 + 1, 47), x1 = min(x0 + 1, 47);
    const float* sp = src + (size_t)nc * 2304;
    float v00 = sp[y0 * 48 + x0], v01 = sp[y0 * 48 + x1];
    float v10 = sp[y1 * 48 + x0], v11 = sp[y1 * 48 + x1];
    float v = (v00 * (1.f - wx) + v01 * wx) * (1.f - wy)
            + (v10 * (1.f - wx) + v11 * wx) * wy;
    if (bnp) {
        float s, t; bn_coef(bnp, C, c, s, t);
        v = fmaxf(fmaf(v, s, t), 0.f);
    }
    dst[idx] = v;
}

// ---------------- energy + softmax -> att [n,9216,9] ---------------------------
// 4-way channel split; BN+ReLU of q fused into the load (reads raw qacc).
__global__ __launch_bounds__(256) void k_attention(const float* __restrict__ qa,
                                                   const float* __restrict__ bnp,
                                                   const float* __restrict__ kf,
                                                   float* __restrict__ att) {
    const int wv = threadIdx.x >> 6;        // channel quarter 0..3
    const int ln = threadIdx.x & 63;
    const int p_abs = blockIdx.x * 64 + ln; // 0..18431
    const int n = p_abs / 9216, p = p_abs % 9216;
    const int y = p / 96, x = p % 96;
    const float* qb = qa + ((size_t)(n * 64 + wv * 16)) * 9216 + p;
    float qv[16];
#pragma unroll
    for (int c = 0; c < 16; ++c) {
        float s, t; bn_coef(bnp, 64, wv * 16 + c, s, t);
        qv[c] = fmaxf(fmaf(qb[(size_t)c * 9216], s, t), 0.f);
    }
    const float* kb = kf + ((size_t)(n * 64 + wv * 16)) * 9216;
    float e[9];
#pragma unroll
    for (int ky = 0; ky < 3; ++ky)
#pragma unroll
        for (int kx = 0; kx < 3; ++kx) {
            int yy = y + 2 * ky - 2, xx = x + 2 * kx - 2;
            float s = 0.f;
            if (yy >= 0 && yy < 96 && xx >= 0 && xx < 96) {
                const float* kp = kb + yy * 96 + xx;
#pragma unroll
                for (int c = 0; c < 16; ++c) s = fmaf(qv[c], kp[(size_t)c * 9216], s);
            }
            e[ky * 3 + kx] = s;
        }
    __shared__ float pe[9][4][64];
#pragma unroll
    for (int k = 0; k < 9; ++k) pe[k][wv][ln] = e[k];
    __syncthreads();
    if (threadIdx.x < 64) {
        float ee[9];
#pragma unroll
        for (int k = 0; k < 9; ++k)
            ee[k] = (pe[k][0][ln] + pe[k][1][ln]) + (pe[k][2][ln] + pe[k][3][ln]);
        float m = ee[0];
#pragma unroll
        for (int k = 1; k < 9; ++k) m = fmaxf(m, ee[k]);
        float sum = 0.f;
#pragma unroll
        for (int k = 0; k < 9; ++k) { ee[k] = __expf(ee[k] - m); sum += ee[k]; }
        float inv = 1.f / sum;
        float* ap = att + (size_t)p_abs * 9;
#pragma unroll
        for (int k = 0; k < 9; ++k) ap[k] = ee[k] * inv;
    }
}

// ---------------- adaptive avg pools s=1,2,3,6 -> pooled [n,2048,50] ------------
__global__ __launch_bounds__(64) void k_pool(const float* __restrict__ xin,
                                             float* __restrict__ pooled) {
    int b = blockIdx.x;            // n*2048+c
    int t = threadIdx.x;
    __shared__ float cells[50];
    if (t < 50) cells[t] = 0.f;
    __syncthreads();
    float rs = 0.f;
    if (t < 48) {
        const f32x4* rowv = (const f32x4*)(xin + (size_t)b * 2304 + t * 48);
        float s6[6];
#pragma unroll
        for (int j = 0; j < 6; ++j) {
            f32x4 u = rowv[2 * j], v = rowv[2 * j + 1];
            s6[j] = ((u[0] + u[1]) + (u[2] + u[3])) + ((v[0] + v[1]) + (v[2] + v[3]));
        }
        float s3a = s6[0] + s6[1], s3b = s6[2] + s6[3], s3c = s6[4] + s6[5];
        float s2a = s3a + s6[2], s2b = s6[3] + s3c;
        rs = s2a + s2b;
        int r6 = t >> 3, r3 = t >> 4, r2 = t / 24;
        atomicAdd(&cells[14 + r6 * 6 + 0], s6[0]);
        atomicAdd(&cells[14 + r6 * 6 + 1], s6[1]);
        atomicAdd(&cells[14 + r6 * 6 + 2], s6[2]);
        atomicAdd(&cells[14 + r6 * 6 + 3], s6[3]);
        atomicAdd(&cells[14 + r6 * 6 + 4], s6[4]);
        atomicAdd(&cells[14 + r6 * 6 + 5], s6[5]);
        atomicAdd(&cells[5 + r3 * 3 + 0], s3a);
        atomicAdd(&cells[5 + r3 * 3 + 1], s3b);
        atomicAdd(&cells[5 + r3 * 3 + 2], s3c);
        atomicAdd(&cells[1 + r2 * 2 + 0], s2a);
        atomicAdd(&cells[1 + r2 * 2 + 1], s2b);
    }
#pragma unroll
    for (int off = 32; off > 0; off >>= 1) rs += __shfl_down(rs, off);
    if (t == 0) atomicAdd(&cells[0], rs);
    __syncthreads();
    if (t < 50) {
        float inv = (t == 0) ? (1.f / 2304.f)
                  : (t < 5)  ? (1.f / 576.f)
                  : (t < 14) ? (1.f / 256.f)
                             : (1.f / 64.f);
        pooled[(size_t)b * 50 + t] = cells[t] * inv;
    }
}

// ---------------- pconv2: 1x1 conv 2048->512 per cell + BN + ReLU ---------------
__global__ __launch_bounds__(64) void k_pconv2(const float* __restrict__ pooled,
        const float* __restrict__ wp1, const float* __restrict__ bn1,
        const float* __restrict__ wp2, const float* __restrict__ bn2,
        const float* __restrict__ wp3, const float* __restrict__ bn3,
        const float* __restrict__ wp4, const float* __restrict__ bn4,
        float* __restrict__ pconv) {
    const int co = blockIdx.x, n = blockIdx.y;
    const int t = threadIdx.x;
    const int cell = (t < 50) ? t : 49;
    const float* w; const float* bnp;
    if (cell == 0)      { w = wp1; bnp = bn1; }
    else if (cell < 5)  { w = wp2; bnp = bn2; }
    else if (cell < 14) { w = wp3; bnp = bn3; }
    else                { w = wp4; bnp = bn4; }
    const float* pin = pooled + (size_t)n * 2048 * 50 + cell;
    const float* wr = w + (size_t)co * 2048;
    float a0 = 0.f, a1 = 0.f, a2 = 0.f, a3 = 0.f;
    for (int c = 0; c < 2048; c += 4) {
        a0 = fmaf(pin[(size_t)c * 50],       wr[c],     a0);
        a1 = fmaf(pin[(size_t)(c + 1) * 50], wr[c + 1], a1);
        a2 = fmaf(pin[(size_t)(c + 2) * 50], wr[c + 2], a2);
        a3 = fmaf(pin[(size_t)(c + 3) * 50], wr[c + 3], a3);
    }
    float a = (a0 + a1) + (a2 + a3);
    float s, tt; bn_coef(bnp, 512, co, s, tt);
    if (t < 50)
        pconv[((size_t)n * 512 + co) * 50 + cell] = fmaxf(fmaf(a, s, tt), 0.f);
}

// ---------------- w_c5 -> wt (ci<2048) AND wpsp (ci>=2048), one launch ----------
__global__ __launch_bounds__(256) void k_wtrans_all(const float* __restrict__ w5,
                                                    hbf* __restrict__ wt,
                                                    hbf* __restrict__ wpsp) {
    int b = blockIdx.x;
    if (b < 4096) {       // wt: [tap][512 co][2048 ci]
        int idx = b * 256 + threadIdx.x;   // 512*2048
        int co = idx >> 11, ci = idx & 2047;
        const float* s = w5 + ((size_t)co * 4096 + ci) * 9;
#pragma unroll
        for (int tap = 0; tap < 9; ++tap)
            wt[((size_t)(tap * 512 + co)) * 2048 + ci] = __float2bfloat16(s[tap]);
    } else {              // wpsp: [tap][4 b][512 c][512 co]
        int r = b - 4096;                   // 0..255, decode (x=8, y=4, z=8)
        const int co = (r & 7) * 64 + (threadIdx.x & 63);
        const int bb = (r >> 3) & 3;
        const int c0 = (r >> 5) * 64 + (threadIdx.x >> 6) * 16;
        for (int i = 0; i < 16; ++i) {
            int c = c0 + i;
            const float* s = w5 + ((size_t)co * 4096 + 2048 + bb * 512 + c) * 9;
#pragma unroll
            for (int tap = 0; tap < 9; ++tap)
                wpsp[(((size_t)(tap * 4 + bb) * 512) + c) * 512 + co] = __float2bfloat16(s[tap]);
        }
    }
}

// ---------------- computeM2: M[n,co,tap,cell] via coalesced bf16 weights --------
__global__ __launch_bounds__(64) void k_computeM2(const hbf* __restrict__ wpsp,
                                                  const float* __restrict__ pconv,
                                                  float* __restrict__ M) {
    const int cog = blockIdx.x, tap = blockIdx.y;
    const int n = blockIdx.z / 7, chunk = blockIdx.z % 7;
    const int cell0_t[7] = {0, 1, 5, 14, 23, 32, 41};
    const int ncell_t[7] = {1, 4, 9, 9, 9, 9, 9};
    const int btab[7]    = {0, 1, 2, 3, 3, 3, 3};
    const int cell0 = cell0_t[chunk], nc = ncell_t[chunk], b = btab[chunk];
    const int co = cog * 64 + threadIdx.x;
    const hbf* wb = wpsp + ((size_t)(tap * 4 + b) * 512) * 512 + co;
    const float* pc = pconv + (size_t)n * 512 * 50 + cell0;
    float acc[9];
#pragma unroll
    for (int j = 0; j < 9; ++j) acc[j] = 0.f;
    for (int c = 0; c < 512; ++c) {
        float w = __bfloat162float(wb[(size_t)c * 512]);
#pragma unroll
        for (int j = 0; j < 9; ++j)          // cells 0..8 past cell0 always in-bounds
            acc[j] = fmaf(w, pc[c * 50 + j], acc[j]);
    }
    float* Mp = M + ((size_t)(n * 512 + co) * 9 + tap) * 50 + cell0;
    for (int j = 0; j < nc; ++j) Mp[j] = acc[j];
}

// bilinear cell coefficients for branch with grid s x s at pixel (yy,xx) in 48x48
struct B4 { int c0, c1, c2, c3; float w0, w1, w2, w3; };
__device__ __forceinline__ B4 cell_interp(int yy, int xx, int s, int base) {
    int sm1 = s - 1;
    int yn = yy * sm1, xn = xx * sm1;
    int y0 = yn / 47, x0 = xn / 47;
    float wy = (float)(yn - y0 * 47) * (1.f / 47.f);
    float wx = (float)(xn - x0 * 47) * (1.f / 47.f);
    int y1 = min(y0 + 1, sm1), x1 = min(x0 + 1, sm1);
    B4 r;
    r.c0 = base + y0 * s + x0; r.c1 = base + y0 * s + x1;
    r.c2 = base + y1 * s + x0; r.c3 = base + y1 * s + x1;
    r.w0 = (1.f - wy) * (1.f - wx); r.w1 = (1.f - wy) * wx;
    r.w2 = wy * (1.f - wx);         r.w3 = wy * wx;
    return r;
}

// ---------------- x (fp32 [n,2048,48,48]) -> xtp (bf16 [n,50*50,2048], pad=0) ---
__global__ __launch_bounds__(256) void k_xtrans(const float* __restrict__ x,
                                                hbf* __restrict__ xtp) {
    __shared__ float tbuf[32][33];
    const int p0 = blockIdx.x * 32, c0 = blockIdx.y * 32, n = blockIdx.z;
    const int tx = threadIdx.x, ty = threadIdx.y;
#pragma unroll
    for (int i = 0; i < 4; ++i) {
        int ci = c0 + ty * 4 + i;
        tbuf[ty * 4 + i][tx] = x[((size_t)(n * 2048 + ci)) * 2304 + p0 + tx];
    }
    __syncthreads();
#pragma unroll
    for (int i = 0; i < 4; ++i) {
        int p = p0 + ty * 4 + i;
        int pp = (p / 48 + 1) * 50 + (p % 48) + 1;
        xtp[((size_t)(n * 2500 + pp)) * 2048 + c0 + tx] = __float2bfloat16(tbuf[tx][ty * 4 + i]);
    }
}

// ---------------- conv5 direct part: MFMA implicit GEMM, tap-fused, pipelined ---
__global__ __launch_bounds__(256) void k_conv5_mfma(const hbf* __restrict__ wt,
                                                    const hbf* __restrict__ xtp,
                                                    float* __restrict__ c5acc) {
    __shared__ hbf As[2][3][128 * 32];   // 2 x 24KB
    __shared__ hbf Bs[2][136 * 32];      // 2 x 8.5KB
    const int tid = threadIdx.x;
    const int l = tid & 63, w = tid >> 6;
    const int m0 = blockIdx.x * 128;
    const int P0 = blockIdx.y * 128;
    const int g  = blockIdx.z;               // tap row (dy = g-1)
    const int n_img = P0 / 2304;
    const int pbase = P0 - n_img * 2304;
    const int r0 = tid >> 2;
    const int swzk = ((tid & 3) ^ ((r0 >> 1) & 3)) * 8;

    const int pp0 = pbase + 2 * (pbase / 48) + 51;
    const ptrdiff_t browbase = (ptrdiff_t)n_img * 2500 + pp0 + (g - 1) * 50 - 1;

    const int wm = (w & 1) * 64, wn = (w >> 1) * 64;
    int jb[4];
#pragma unroll
    for (int tj = 0; tj < 4; ++tj) {
        int p = pbase + wn + tj * 16 + (l & 15);
        jb[tj] = p + 2 * (p / 48) + 51 - pp0;          // 0..133
    }
    const int slotA = ((l >> 4) ^ ((l >> 1) & 3)) * 8;

    f32x4 acc[4][4];
#pragma unroll
    for (int i = 0; i < 4; ++i)
#pragma unroll
        for (int j = 0; j < 4; ++j) acc[i][j] = {0.f, 0.f, 0.f, 0.f};

    const hbf* gA = wt + ((size_t)(g * 1536 + m0 + r0)) * 2048 + swzk;
    const hbf* gB = xtp + (size_t)(browbase + r0) * 2048 + swzk;

#define STAGE5(buf, k0) do {                                                       \
        hbf* ldsA_ = &As[buf][0][0] + w * 512;                                     \
        hbf* ldsB_ = &Bs[buf][0] + w * 512;                                        \
        _Pragma("unroll")                                                          \
        for (int t_ = 0; t_ < 3; ++t_) {                                           \
            GLDS(gA + (size_t)t_ * 512 * 2048 + (k0),             ldsA_ + t_ * 4096);      \
            GLDS(gA + (size_t)t_ * 512 * 2048 + 64 * 2048 + (k0), ldsA_ + t_ * 4096 + 2048); \
        }                                                                          \
        GLDS(gB + (k0),                      ldsB_);                               \
        GLDS(gB + (size_t)64 * 2048 + (k0),  ldsB_ + 2048);                        \
        if (tid < 32)                                                              \
            GLDS(gB + (size_t)128 * 2048 + (k0), &Bs[buf][0] + 4096);              \
    } while (0)

    STAGE5(0, 0);
    int cur = 0;
#pragma unroll 2
    for (int k0 = 0; k0 < 2048; k0 += 32) {
        __syncthreads();   // drains prev stage (issued one compute phase ago)
        if (k0 + 32 < 2048) STAGE5(cur ^ 1, k0 + 32);
        __builtin_amdgcn_s_setprio(1);
#pragma unroll
        for (int t = 0; t < 3; ++t) {
            bf16x8 af[4], bfr[4];
#pragma unroll
            for (int ti = 0; ti < 4; ++ti)
                af[ti] = *(const bf16x8*)(&As[cur][t][(wm + ti * 16 + (l & 15)) * 32 + slotA]);
#pragma unroll
            for (int tj = 0; tj < 4; ++tj) {
                const int brow = jb[tj] + t;
                bfr[tj] = *(const bf16x8*)(&Bs[cur][0] + brow * 32 + (((l >> 4) ^ ((brow >> 1) & 3)) * 8));
            }
#pragma unroll
            for (int ti = 0; ti < 4; ++ti)
#pragma unroll
                for (int tj = 0; tj < 4; ++tj)
                    acc[ti][tj] = __builtin_amdgcn_mfma_f32_16x16x32_bf16(
                        af[ti], bfr[tj], acc[ti][tj], 0, 0, 0);
        }
        __builtin_amdgcn_s_setprio(0);
        cur ^= 1;
    }
#undef STAGE5

#pragma unroll
    for (int ti = 0; ti < 4; ++ti) {
        const int mrow = wm + ti * 16 + (l >> 4) * 4;
#pragma unroll
        for (int tj = 0; tj < 4; ++tj) {
            const int p = pbase + wn + tj * 16 + (l & 15);
            float* dst = c5acc + ((size_t)(n_img * 512 + m0 + mrow)) * 2304 + p;
#pragma unroll
            for (int r = 0; r < 4; ++r)
                atomicAdd(dst + (size_t)r * 2304, acc[ti][tj][r]);
        }
    }
}

// ---------------- epilogue: + psp(M)-part, BN, ReLU -> c5out bf16 ---------------
__global__ __launch_bounds__(256) void k_bnrelu_psp(const float* __restrict__ c5acc,
                                                    const float* __restrict__ M,
                                                    const float* __restrict__ bnp,
                                                    hbf* __restrict__ c5out) {
    const int co = blockIdx.x, n = blockIdx.y;
    __shared__ float Ms[450];
    const float* Mrow = M + ((size_t)(n * 512 + co)) * 450;
    for (int i = threadIdx.x; i < 450; i += 256) Ms[i] = Mrow[i];
    __syncthreads();
    float s, t; bn_coef(bnp, 512, co, s, t);
    const size_t base = ((size_t)(n * 512 + co)) * 2304;
#pragma unroll
    for (int i = 0; i < 9; ++i) {
        int p = threadIdx.x + i * 256;
        int y = p / 48, x = p % 48;
        float a = c5acc[base + p];
#pragma unroll
        for (int ky = 0; ky < 3; ++ky) {
            int yy = y + ky - 1;
            if (yy < 0 || yy > 47) continue;
#pragma unroll
            for (int kx = 0; kx < 3; ++kx) {
                int xx = x + kx - 1;
                if (xx < 0 || xx > 47) continue;
                const float* Mp = Ms + (ky * 3 + kx) * 50;
                float sa = Mp[0];
                B4 b2 = cell_interp(yy, xx, 2, 1);
                B4 b3 = cell_interp(yy, xx, 3, 5);
                B4 b6 = cell_interp(yy, xx, 6, 14);
                sa = fmaf(b2.w0, Mp[b2.c0], sa); sa = fmaf(b2.w1, Mp[b2.c1], sa);
                sa = fmaf(b2.w2, Mp[b2.c2], sa); sa = fmaf(b2.w3, Mp[b2.c3], sa);
                sa = fmaf(b3.w0, Mp[b3.c0], sa); sa = fmaf(b3.w1, Mp[b3.c1], sa);
                sa = fmaf(b3.w2, Mp[b3.c2], sa); sa = fmaf(b3.w3, Mp[b3.c3], sa);
                sa = fmaf(b6.w0, Mp[b6.c0], sa); sa = fmaf(b6.w1, Mp[b6.c1], sa);
                sa = fmaf(b6.w2, Mp[b6.c2], sa); sa = fmaf(b6.w3, Mp[b6.c3], sa);
                a += sa;
            }
        }
        c5out[base + p] = __float2bfloat16(fmaxf(fmaf(a, s, t), 0.f));
    }
}

// ---------------- conv6 at 48x48 (512->59, no bias), 4 px/thread bf16x4 ---------
__global__ __launch_bounds__(192) void k_conv6s(const hbf* __restrict__ c5o,
                                                const float* __restrict__ w,
                                                float* __restrict__ out) {
    const int p4 = blockIdx.y * 192 + threadIdx.x;   // 0..575 (x4 pixels)
    const int n = blockIdx.z;
    const int co = blockIdx.x;
    const hbf* ip = c5o + (size_t)n * 512 * 2304 + p4 * 4;
    const float* wr = w + (size_t)co * 512;
    float a0 = 0.f, a1 = 0.f, a2 = 0.f, a3 = 0.f;
    for (int ci = 0; ci < 512; ++ci) {
        bf16x4 v = *(const bf16x4*)(ip + (size_t)ci * 2304);
        float wv = wr[ci];
        a0 = fmaf((float)v[0], wv, a0);
        a1 = fmaf((float)v[1], wv, a1);
        a2 = fmaf((float)v[2], wv, a2);
        a3 = fmaf((float)v[3], wv, a3);
    }
    f32x4 res = {a0, a1, a2, a3};
    *(f32x4*)(out + ((size_t)n * 59 + co) * 2304 + p4 * 4) = res;
}

// ---------------- final: out = bias + sum_k att[k]*up96(c6s)[tap_k] -------------
// up96(59ch) fused: bilinear of c6s computed on the fly (c6s L2-resident, 1.1MB).
__global__ void k_final(const float* __restrict__ att, const float* __restrict__ c6s,
                        const float* __restrict__ bias, float* __restrict__ out) {
    int idx = blockIdx.x * blockDim.x + threadIdx.x;  // 2*59*9216
    int p = idx % 9216;
    int nc = idx / 9216;
    int cls = nc % 59, n = nc / 59;
    int y = p / 96, x = p % 96;
    const float* ar = att + ((size_t)n * 9216 + p) * 9;
    const float* cp = c6s + (size_t)nc * 2304;
    int xs0[3], xs1[3], ys0[3], ys1[3];
    float fx[3], fy[3];
#pragma unroll
    for (int d = 0; d < 3; ++d) {
        int xx = x + 2 * d - 2;
        if (xx >= 0 && xx < 96) {
            int xn = xx * 47, x0 = xn / 95;
            xs0[d] = x0; xs1[d] = min(x0 + 1, 47);
            fx[d] = (float)(xn - x0 * 95) * (1.f / 95.f);
        } else { xs0[d] = -1; xs1[d] = 0; fx[d] = 0.f; }
        int yy = y + 2 * d - 2;
        if (yy >= 0 && yy < 96) {
            int yn = yy * 47, y0 = yn / 95;
            ys0[d] = y0; ys1[d] = min(y0 + 1, 47);
            fy[d] = (float)(yn - y0 * 95) * (1.f / 95.f);
        } else { ys0[d] = -1; ys1[d] = 0; fy[d] = 0.f; }
    }
    float a = bias[cls];
#pragma unroll
    for (int ky = 0; ky < 3; ++ky) {
        if (ys0[ky] < 0) continue;
        const float* r0 = cp + ys0[ky] * 48;
        const float* r1 = cp + ys1[ky] * 48;
        float wy = fy[ky];
#pragma unroll
        for (int kx = 0; kx < 3; ++kx) {
            if (xs0[kx] < 0) continue;
            float wx = fx[kx];
            float v0 = r0[xs0[kx]] * (1.f - wx) + r0[xs1[kx]] * wx;
            float v1 = r1[xs0[kx]] * (1.f - wx) + r1[xs1[kx]] * wx;
            a = fmaf(ar[ky * 3 + kx], v0 * (1.f - wy) + v1 * wy, a);
        }
    }
    out[idx] = a;
}

extern "C" void kernel_launch(void* const* d_in, const int* in_sizes, int n_in,
                              void* d_out, int out_size, void* d_ws, size_t ws_size,
                              hipStream_t stream) {
    const float* c1    = (const float*)d_in[0];
    const float* c2    = (const float*)d_in[1];
    const float* xin   = (const float*)d_in[2];
    const float* w_r1  = (const float*)d_in[3];
    const float* bn_r1 = (const float*)d_in[4];
    const float* w_r2  = (const float*)d_in[5];
    const float* bn_r2 = (const float*)d_in[6];
    const float* w_r3  = (const float*)d_in[7];
    const float* bn_r3 = (const float*)d_in[8];
    const float* w_p1  = (const float*)d_in[9];
    const float* bn_p1 = (const float*)d_in[10];
    const float* w_p2  = (const float*)d_in[11];
    const float* bn_p2 = (const float*)d_in[12];
    const float* w_p3  = (const float*)d_in[13];
    const float* bn_p3 = (const float*)d_in[14];
    const float* w_p4  = (const float*)d_in[15];
    const float* bn_p4 = (const float*)d_in[16];
    const float* w_c5  = (const float*)d_in[17];
    const float* bn_c5 = (const float*)d_in[18];
    const float* w_c6  = (const float*)d_in[19];
    const float* b_c6  = (const float*)d_in[20];
    float* out = (float*)d_out;
    (void)in_sizes; (void)n_in; (void)out_size; (void)ws_size;

    char* base = (char*)d_ws;
    float* att = (float*)base;                    // 663,552 B
    char*  A   = base + 663552;
    // ---- phase 1 layout (region A) ----
    hbf*   c1t   = (hbf*)A;                       // 10,240,000
    hbf*   r1t   = (hbf*)(A + 10240000);          //  2,560,000
    float* r1acc = (float*)(A + 12800000);        //  4,718,592
    float* qacc  = (float*)(A + 17518592);        //  4,718,592
    float* c2acc = (float*)(A + 22237184);        //  1,179,648  (fill ends 23,416,832)
    float* c2r   = (float*)(A + 28135424);        //  4,718,592
    hbf*   wr1t  = (hbf*)(A + 32854016);          //    294,912
    hbf*   wr2t  = (hbf*)(A + 33148928);          //     73,728  (ends 33,222,656)
    // ---- phase 2 early (region A): wpsp aliased under xtp, consumed pre-fill ----
    hbf*   wpsp   = (hbf*)A;                      // 18,874,368 (< xtp's 20,480,000)
    float* pooled = (float*)(A + 48791552);       //    819,200
    float* pconv  = (float*)(A + 49610752);       //    204,800
    float* M      = (float*)(A + 49815552);       //  1,843,200  (ends 51,658,752)
    // ---- phase 2 main (region A, reuses wpsp space) ----
    hbf*   xtp    = (hbf*)A;                      // 20,480,000
    float* c5acc  = (float*)(A + 20480000);       //  9,437,184
    hbf*   wt     = (hbf*)(A + 29917184);         // 18,874,368
    // ---- phase 2b (after conv5), aliased over xtp ----
    hbf*   c5out = (hbf*)A;                       //  4,718,592
    float* c6s   = (float*)(A + 4718592);         //  1,087,488
    // total ws: 663,552 + 51,658,752 = 52,322,304 B (unchanged)

    // ---- phase 1: attention branch ----
    k_fill0<<<dim3(22868), 256, 0, stream>>>((uint32_t*)A, 5854208);
    k_c1trans<<<dim3(288, 8, 2), dim3(32, 8), 0, stream>>>(c1, c1t);
    k_wsmall<<<dim3(80), 256, 0, stream>>>(w_r1, wr1t, w_r2, wr2t);
    k_dconv_mfma<256><<<dim3(288, 3), 256, 0, stream>>>(wr1t, c1t, r1acc);
    k_ep_r1<<<dim3(288), 256, 0, stream>>>(r1acc, bn_r1, r1t);
    k_dconv_mfma<64><<<dim3(288, 3), 256, 0, stream>>>(wr2t, r1t, qacc);
    k_conv1x1_c2<<<dim3(8, 12, 8), dim3(48, 4), 0, stream>>>(c2, w_r3, c2acc);
    k_up96<<<dim3(2 * 64 * 9216 / 256), 256, 0, stream>>>(c2acc, c2r, 64, bn_r3);
    k_attention<<<dim3(288), 256, 0, stream>>>(qacc, bn_r2, c2r, att);
    // ---- phase 2: psp branch ----
    k_pool<<<dim3(4096), 64, 0, stream>>>(xin, pooled);
    k_pconv2<<<dim3(512, 2), 64, 0, stream>>>(pooled, w_p1, bn_p1, w_p2, bn_p2,
                                              w_p3, bn_p3, w_p4, bn_p4, pconv);
    k_wtrans_all<<<dim3(4352), 256, 0, stream>>>(w_c5, wt, wpsp);
    k_computeM2<<<dim3(8, 9, 14), 64, 0, stream>>>(wpsp, pconv, M);
    k_fill0<<<dim3(29216), 256, 0, stream>>>((uint32_t*)xtp, 7479296);
    k_xtrans<<<dim3(72, 64, 2), dim3(32, 8), 0, stream>>>(xin, xtp);
    k_conv5_mfma<<<dim3(4, 36, 3), 256, 0, stream>>>(wt, xtp, c5acc);
    k_bnrelu_psp<<<dim3(512, 2), 256, 0, stream>>>(c5acc, M, bn_c5, c5out);
    // classifier (conv6 commuted before upsample) + attention aggregation
    k_conv6s<<<dim3(59, 3, 2), 192, 0, stream>>>(c5out, w_c6, c6s);
    k_final<<<dim3(2 * 59 * 9216 / 256), 256, 0, stream>>>(att, c6s, b_c6, out);
}

// Round 6
// 661.655 us; speedup vs baseline: 1.0346x; 1.0346x over previous
//
#include <hip/hip_runtime.h>
#include <hip/hip_bf16.h>
#include <cstddef>
#include <cstdint>

typedef __hip_bfloat16 hbf;
typedef __bf16 bf16x8 __attribute__((ext_vector_type(8)));
typedef __bf16 bf16x4 __attribute__((ext_vector_type(4)));
typedef float f32x4 __attribute__((ext_vector_type(4)));

#define GLDS(gp, lp) __builtin_amdgcn_global_load_lds( \
    (const __attribute__((address_space(1))) void*)(gp), \
    (__attribute__((address_space(3))) void*)(lp), 16, 0, 0)

// bn: y = x*s + t, s = g*rsqrt(v+eps), t = b - m*s
__device__ __forceinline__ void bn_coef(const float* __restrict__ p, int C, int c,
                                        float& s, float& t) {
    float g = p[c];
    float b = p[C + c];
    float m = p[2 * C + c];
    float v = p[3 * C + c];
    s = g * rsqrtf(v + 1e-5f);
    t = b - m * s;
}

// ---------------- zero-fill (dwords) --------------------------------------------
__global__ void k_fill0(uint32_t* __restrict__ p, int n) {
    int i = blockIdx.x * blockDim.x + threadIdx.x;
    if (i < n) p[i] = 0u;
}

// ---------------- c1 fp32 [2,256,96,96] -> c1t bf16 [n][100*100][256], pad=2 ----
__global__ __launch_bounds__(256) void k_c1trans(const float* __restrict__ x,
                                                 hbf* __restrict__ c1t) {
    __shared__ float tbuf[32][33];
    const int p0 = blockIdx.x * 32, c0 = blockIdx.y * 32, n = blockIdx.z;
    const int tx = threadIdx.x, ty = threadIdx.y;
#pragma unroll
    for (int i = 0; i < 4; ++i) {
        int ci = c0 + ty * 4 + i;
        tbuf[ty * 4 + i][tx] = x[((size_t)(n * 256 + ci)) * 9216 + p0 + tx];
    }
    __syncthreads();
#pragma unroll
    for (int i = 0; i < 4; ++i) {
        int p = p0 + ty * 4 + i;
        int pp = (p / 96 + 2) * 100 + (p % 96) + 2;
        c1t[((size_t)(n * 10000 + pp)) * 256 + c0 + tx] = __float2bfloat16(tbuf[tx][ty * 4 + i]);
    }
}

// ---------------- both small conv weights -> [tap][64][CI] bf16, one launch -----
__global__ __launch_bounds__(256) void k_wsmall(const float* __restrict__ w1,
                                                hbf* __restrict__ wt1,
                                                const float* __restrict__ w2,
                                                hbf* __restrict__ wt2) {
    int b = blockIdx.x;
    if (b < 64) {           // w_r1: [64][256][3][3]
        int idx = b * 256 + threadIdx.x;
        int co = idx >> 8, ci = idx & 255;
        const float* s = w1 + ((size_t)(co * 256 + ci)) * 9;
#pragma unroll
        for (int tap = 0; tap < 9; ++tap)
            wt1[((size_t)(tap * 64 + co)) * 256 + ci] = __float2bfloat16(s[tap]);
    } else {                // w_r2: [64][64][3][3]
        int idx = (b - 64) * 256 + threadIdx.x;
        int co = idx >> 6, ci = idx & 63;
        const float* s = w2 + ((size_t)(co * 64 + ci)) * 9;
#pragma unroll
        for (int tap = 0; tap < 9; ++tap)
            wt2[((size_t)(tap * 64 + co)) * 64 + ci] = __float2bfloat16(s[tap]);
    }
}

// ---------------- dilated 3x3 conv (d=2) MFMA, tap-fused, 64co x 128px tile -----
// conv5's proven wide-tile geometry: union B of 140 padded rows covers all 3 tap
// col-shifts for 128 px; 24 MFMA/wave/k-step (was 12) at same A staging cost.
template <int CI>
__global__ __launch_bounds__(256) void k_dconv_mfma(const hbf* __restrict__ wt,
                                                    const hbf* __restrict__ it,
                                                    float* __restrict__ accout) {
    __shared__ hbf As[2][3][64 * 32];   // per-tap weights [64 co][32 k]
    __shared__ hbf Bs[2][140 * 32];     // union of 128-px padded rows + shifts
    const int tid = threadIdx.x;
    const int l = tid & 63, w = tid >> 6;
    const int P0 = blockIdx.x * 128;
    const int g  = blockIdx.y;                 // tap row (dy = 2g-2)
    const int r0 = tid >> 2;
    const int swzk = ((tid & 3) ^ ((r0 >> 1) & 3)) * 8;

    const int n_i = P0 / 9216;
    const int pl0 = P0 - n_i * 9216;
    const int pp0 = (pl0 / 96 + 2) * 100 + (pl0 % 96) + 2;
    const ptrdiff_t browbase = (ptrdiff_t)n_i * 10000 + pp0 + (g - 1) * 200 - 2;

    const int wn = w * 32;
    int jb[2];
#pragma unroll
    for (int tj = 0; tj < 2; ++tj) {
        int pl_lane = pl0 + wn + tj * 16 + (l & 15);
        jb[tj] = ((pl_lane / 96 + 2) * 100 + (pl_lane % 96) + 2) - pp0;  // 0..135
    }
    const int slotA = ((l >> 4) ^ ((l >> 1) & 3)) * 8;

    f32x4 acc[4][2];
#pragma unroll
    for (int i = 0; i < 4; ++i)
#pragma unroll
        for (int j = 0; j < 2; ++j) acc[i][j] = {0.f, 0.f, 0.f, 0.f};

    const hbf* gA = wt + ((size_t)(g * 192 + r0)) * CI + swzk;
    const hbf* gB = it + (size_t)(browbase + r0) * CI + swzk;

#define STAGE_D(buf, k0) do {                                                  \
        hbf* ldsA_ = &As[buf][0][0] + w * 512;                                 \
        hbf* ldsB_ = &Bs[buf][0] + w * 512;                                    \
        _Pragma("unroll")                                                      \
        for (int t_ = 0; t_ < 3; ++t_)                                         \
            GLDS(gA + (size_t)t_ * 64 * CI + (k0), ldsA_ + t_ * 2048);         \
        GLDS(gB + (k0), ldsB_);                                                \
        GLDS(gB + (size_t)64 * CI + (k0), ldsB_ + 2048);                       \
        if (tid < 48)                                                          \
            GLDS(gB + (size_t)128 * CI + (k0), &Bs[buf][0] + 4096);            \
    } while (0)

    STAGE_D(0, 0);
    int cur = 0;
#pragma unroll 2
    for (int k0 = 0; k0 < CI; k0 += 32) {
        __syncthreads();   // drains prev stage (issued one compute phase ago)
        if (k0 + 32 < CI) STAGE_D(cur ^ 1, k0 + 32);
#pragma unroll
        for (int t = 0; t < 3; ++t) {
            bf16x8 af[4], bfr[2];
#pragma unroll
            for (int ti = 0; ti < 4; ++ti)
                af[ti] = *(const bf16x8*)(&As[cur][t][(ti * 16 + (l & 15)) * 32 + slotA]);
#pragma unroll
            for (int tj = 0; tj < 2; ++tj) {
                const int brow = jb[tj] + 2 * t;
                bfr[tj] = *(const bf16x8*)(&Bs[cur][0] + brow * 32 + (((l >> 4) ^ ((brow >> 1) & 3)) * 8));
            }
#pragma unroll
            for (int ti = 0; ti < 4; ++ti)
#pragma unroll
                for (int tj = 0; tj < 2; ++tj)
                    acc[ti][tj] = __builtin_amdgcn_mfma_f32_16x16x32_bf16(
                        af[ti], bfr[tj], acc[ti][tj], 0, 0, 0);
        }
        cur ^= 1;
    }
#undef STAGE_D

#pragma unroll
    for (int ti = 0; ti < 4; ++ti) {
        const int mrow = ti * 16 + (l >> 4) * 4;
#pragma unroll
        for (int tj = 0; tj < 2; ++tj) {
            const int px = P0 + wn + tj * 16 + (l & 15);
            const int n2 = px / 9216, pl2 = px % 9216;
            float* dst = accout + ((size_t)(n2 * 64 + mrow)) * 9216 + pl2;
#pragma unroll
            for (int r = 0; r < 4; ++r)
                atomicAdd(dst + (size_t)r * 9216, acc[ti][tj][r]);
        }
    }
}

// ---------------- ep_r1: BN+ReLU(r1acc) -> r1t bf16 padded-transposed -----------
__global__ __launch_bounds__(256) void k_ep_r1(const float* __restrict__ acc,
                                               const float* __restrict__ bnp,
                                               hbf* __restrict__ r1t) {
    const int q = threadIdx.x >> 6;         // channel quarter
    const int ln = threadIdx.x & 63;
    const int pi = blockIdx.x * 64 + ln;    // 0..18431
    const int n = pi / 9216, pl = pi % 9216;
    const int pp = (pl / 96 + 2) * 100 + (pl % 96) + 2;
    hbf* dst = r1t + ((size_t)(n * 10000 + pp)) * 64 + q * 16;
    const float* src = acc + (size_t)(n * 64 + q * 16) * 9216 + pl;
#pragma unroll
    for (int i = 0; i < 16; ++i) {
        float s, t; bn_coef(bnp, 64, q * 16 + i, s, t);
        dst[i] = __float2bfloat16(fmaxf(fmaf(src[(size_t)i * 9216], s, t), 0.f));
    }
}

// ---------------- 1x1 conv on c2 (512->64), ci split 4-ways, atomic -------------
__global__ __launch_bounds__(192) void k_conv1x1_c2(const float* __restrict__ c2,
                                                    const float* __restrict__ w,
                                                    float* __restrict__ outacc) {
    const int x = threadIdx.x;
    const int y = blockIdx.y * 4 + threadIdx.y;
    const int n = blockIdx.z >> 2;
    const int ci0 = (blockIdx.z & 3) * 128;
    const int cg = blockIdx.x;
    const int p = y * 48 + x;
    float acc[8];
#pragma unroll
    for (int j = 0; j < 8; ++j) acc[j] = 0.f;
    for (int ci = ci0; ci < ci0 + 128; ++ci) {
        float iv = c2[(size_t)(n * 512 + ci) * 2304 + p];
#pragma unroll
        for (int j = 0; j < 8; ++j)
            acc[j] = fmaf(iv, w[(size_t)(cg * 8 + j) * 512 + ci], acc[j]);
    }
#pragma unroll
    for (int j = 0; j < 8; ++j)
        atomicAdd(&outacc[(size_t)(n * 64 + cg * 8 + j) * 2304 + p], acc[j]);
}

// ---------------- bilinear 48->96 (align_corners), optional BN+ReLU -------------
__global__ void k_up96(const float* __restrict__ src, float* __restrict__ dst,
                       int C, const float* __restrict__ bnp) {
    int idx = blockIdx.x * blockDim.x + threadIdx.x;  // 2*C*9216
    int p = idx % 9216;
    int nc = idx / 9216;
    int c = nc % C;
    int y = p / 96, x = p % 96;
    int yn = y * 47, xn = x * 47;
    int y0 = yn / 95, x0 = xn / 95;
    float wy = (float)(yn - y0 * 95) * (1.f / 95.f);
    float wx = (float)(xn - x0 * 95) * (1.f / 95.f);
    int y1 = min(y0 + 1, 47), x1 = min(x0 + 1, 47);
    const float* sp = src + (size_t)nc * 2304;
    float v00 = sp[y0 * 48 + x0], v01 = sp[y0 * 48 + x1];
    float v10 = sp[y1 * 48 + x0], v11 = sp[y1 * 48 + x1];
    float v = (v00 * (1.f - wx) + v01 * wx) * (1.f - wy)
            + (v10 * (1.f - wx) + v11 * wx) * wy;
    if (bnp) {
        float s, t; bn_coef(bnp, C, c, s, t);
        v = fmaxf(fmaf(v, s, t), 0.f);
    }
    dst[idx] = v;
}

// ---------------- energy + softmax -> att [n,9216,9] ---------------------------
__global__ __launch_bounds__(256) void k_attention(const float* __restrict__ qa,
                                                   const float* __restrict__ bnp,
                                                   const float* __restrict__ kf,
                                                   float* __restrict__ att) {
    const int wv = threadIdx.x >> 6;        // channel quarter 0..3
    const int ln = threadIdx.x & 63;
    const int p_abs = blockIdx.x * 64 + ln; // 0..18431
    const int n = p_abs / 9216, p = p_abs % 9216;
    const int y = p / 96, x = p % 96;
    const float* qb = qa + ((size_t)(n * 64 + wv * 16)) * 9216 + p;
    float qv[16];
#pragma unroll
    for (int c = 0; c < 16; ++c) {
        float s, t; bn_coef(bnp, 64, wv * 16 + c, s, t);
        qv[c] = fmaxf(fmaf(qb[(size_t)c * 9216], s, t), 0.f);
    }
    const float* kb = kf + ((size_t)(n * 64 + wv * 16)) * 9216;
    float e[9];
#pragma unroll
    for (int ky = 0; ky < 3; ++ky)
#pragma unroll
        for (int kx = 0; kx < 3; ++kx) {
            int yy = y + 2 * ky - 2, xx = x + 2 * kx - 2;
            float s = 0.f;
            if (yy >= 0 && yy < 96 && xx >= 0 && xx < 96) {
                const float* kp = kb + yy * 96 + xx;
#pragma unroll
                for (int c = 0; c < 16; ++c) s = fmaf(qv[c], kp[(size_t)c * 9216], s);
            }
            e[ky * 3 + kx] = s;
        }
    __shared__ float pe[9][4][64];
#pragma unroll
    for (int k = 0; k < 9; ++k) pe[k][wv][ln] = e[k];
    __syncthreads();
    if (threadIdx.x < 64) {
        float ee[9];
#pragma unroll
        for (int k = 0; k < 9; ++k)
            ee[k] = (pe[k][0][ln] + pe[k][1][ln]) + (pe[k][2][ln] + pe[k][3][ln]);
        float m = ee[0];
#pragma unroll
        for (int k = 1; k < 9; ++k) m = fmaxf(m, ee[k]);
        float sum = 0.f;
#pragma unroll
        for (int k = 0; k < 9; ++k) { ee[k] = __expf(ee[k] - m); sum += ee[k]; }
        float inv = 1.f / sum;
        float* ap = att + (size_t)p_abs * 9;
#pragma unroll
        for (int k = 0; k < 9; ++k) ap[k] = ee[k] * inv;
    }
}

// ---------------- adaptive avg pools s=1,2,3,6 -> pooled_t [n,50,2048] ----------
// Output TRANSPOSED so pconv2 gets per-thread contiguous rows.
__global__ __launch_bounds__(64) void k_pool(const float* __restrict__ xin,
                                             float* __restrict__ pooled) {
    int b = blockIdx.x;            // n*2048+c
    int t = threadIdx.x;
    __shared__ float cells[50];
    if (t < 50) cells[t] = 0.f;
    __syncthreads();
    float rs = 0.f;
    if (t < 48) {
        const f32x4* rowv = (const f32x4*)(xin + (size_t)b * 2304 + t * 48);
        float s6[6];
#pragma unroll
        for (int j = 0; j < 6; ++j) {
            f32x4 u = rowv[2 * j], v = rowv[2 * j + 1];
            s6[j] = ((u[0] + u[1]) + (u[2] + u[3])) + ((v[0] + v[1]) + (v[2] + v[3]));
        }
        float s3a = s6[0] + s6[1], s3b = s6[2] + s6[3], s3c = s6[4] + s6[5];
        float s2a = s3a + s6[2], s2b = s6[3] + s3c;
        rs = s2a + s2b;
        int r6 = t >> 3, r3 = t >> 4, r2 = t / 24;
        atomicAdd(&cells[14 + r6 * 6 + 0], s6[0]);
        atomicAdd(&cells[14 + r6 * 6 + 1], s6[1]);
        atomicAdd(&cells[14 + r6 * 6 + 2], s6[2]);
        atomicAdd(&cells[14 + r6 * 6 + 3], s6[3]);
        atomicAdd(&cells[14 + r6 * 6 + 4], s6[4]);
        atomicAdd(&cells[14 + r6 * 6 + 5], s6[5]);
        atomicAdd(&cells[5 + r3 * 3 + 0], s3a);
        atomicAdd(&cells[5 + r3 * 3 + 1], s3b);
        atomicAdd(&cells[5 + r3 * 3 + 2], s3c);
        atomicAdd(&cells[1 + r2 * 2 + 0], s2a);
        atomicAdd(&cells[1 + r2 * 2 + 1], s2b);
    }
#pragma unroll
    for (int off = 32; off > 0; off >>= 1) rs += __shfl_down(rs, off);
    if (t == 0) atomicAdd(&cells[0], rs);
    __syncthreads();
    if (t < 50) {
        float inv = (t == 0) ? (1.f / 2304.f)
                  : (t < 5)  ? (1.f / 576.f)
                  : (t < 14) ? (1.f / 256.f)
                             : (1.f / 64.f);
        pooled[((size_t)(b >> 11) * 50 + t) * 2048 + (b & 2047)] = cells[t] * inv;
    }
}

// ---------------- pconv2: 1x1 conv 2048->512 per cell + BN + ReLU ---------------
// Reads transposed pooled_t[n][cell][2048] as per-thread contiguous f32x4 streams
// (was a 200B-stride 4B gather: 2048 serial L2 hits/thread, latency-bound).
__global__ __launch_bounds__(64) void k_pconv2(const float* __restrict__ pooled_t,
        const float* __restrict__ wp1, const float* __restrict__ bn1,
        const float* __restrict__ wp2, const float* __restrict__ bn2,
        const float* __restrict__ wp3, const float* __restrict__ bn3,
        const float* __restrict__ wp4, const float* __restrict__ bn4,
        float* __restrict__ pconv) {
    const int co = blockIdx.x, n = blockIdx.y;
    const int t = threadIdx.x;
    const int cell = (t < 50) ? t : 49;
    const float* w; const float* bnp;
    if (cell == 0)      { w = wp1; bnp = bn1; }
    else if (cell < 5)  { w = wp2; bnp = bn2; }
    else if (cell < 14) { w = wp3; bnp = bn3; }
    else                { w = wp4; bnp = bn4; }
    const float* pin = pooled_t + ((size_t)n * 50 + cell) * 2048;
    const float* wr = w + (size_t)co * 2048;
    float a0 = 0.f, a1 = 0.f, a2 = 0.f, a3 = 0.f;
    for (int c = 0; c < 2048; c += 4) {
        f32x4 v = *(const f32x4*)(pin + c);
        f32x4 ww = *(const f32x4*)(wr + c);
        a0 = fmaf(v[0], ww[0], a0);
        a1 = fmaf(v[1], ww[1], a1);
        a2 = fmaf(v[2], ww[2], a2);
        a3 = fmaf(v[3], ww[3], a3);
    }
    float a = (a0 + a1) + (a2 + a3);
    float s, tt; bn_coef(bnp, 512, co, s, tt);
    if (t < 50)
        pconv[((size_t)n * 512 + co) * 50 + cell] = fmaxf(fmaf(a, s, tt), 0.f);
}

// ---------------- w_c5 -> wt (ci<2048) AND wpsp (ci>=2048), one launch ----------
__global__ __launch_bounds__(256) void k_wtrans_all(const float* __restrict__ w5,
                                                    hbf* __restrict__ wt,
                                                    hbf* __restrict__ wpsp) {
    int b = blockIdx.x;
    if (b < 4096) {       // wt: [tap][512 co][2048 ci]
        int idx = b * 256 + threadIdx.x;   // 512*2048
        int co = idx >> 11, ci = idx & 2047;
        const float* s = w5 + ((size_t)co * 4096 + ci) * 9;
#pragma unroll
        for (int tap = 0; tap < 9; ++tap)
            wt[((size_t)(tap * 512 + co)) * 2048 + ci] = __float2bfloat16(s[tap]);
    } else {              // wpsp: [tap][4 b][512 c][512 co]
        int r = b - 4096;                   // 0..255, decode (x=8, y=4, z=8)
        const int co = (r & 7) * 64 + (threadIdx.x & 63);
        const int bb = (r >> 3) & 3;
        const int c0 = (r >> 5) * 64 + (threadIdx.x >> 6) * 16;
        for (int i = 0; i < 16; ++i) {
            int c = c0 + i;
            const float* s = w5 + ((size_t)co * 4096 + 2048 + bb * 512 + c) * 9;
#pragma unroll
            for (int tap = 0; tap < 9; ++tap)
                wpsp[(((size_t)(tap * 4 + bb) * 512) + c) * 512 + co] = __float2bfloat16(s[tap]);
        }
    }
}

// ---------------- computeM2: M[n,co,tap,cell] via coalesced bf16 weights --------
__global__ __launch_bounds__(64) void k_computeM2(const hbf* __restrict__ wpsp,
                                                  const float* __restrict__ pconv,
                                                  float* __restrict__ M) {
    const int cog = blockIdx.x, tap = blockIdx.y;
    const int n = blockIdx.z / 7, chunk = blockIdx.z % 7;
    const int cell0_t[7] = {0, 1, 5, 14, 23, 32, 41};
    const int ncell_t[7] = {1, 4, 9, 9, 9, 9, 9};
    const int btab[7]    = {0, 1, 2, 3, 3, 3, 3};
    const int cell0 = cell0_t[chunk], nc = ncell_t[chunk], b = btab[chunk];
    const int co = cog * 64 + threadIdx.x;
    const hbf* wb = wpsp + ((size_t)(tap * 4 + b) * 512) * 512 + co;
    const float* pc = pconv + (size_t)n * 512 * 50 + cell0;
    float acc[9];
#pragma unroll
    for (int j = 0; j < 9; ++j) acc[j] = 0.f;
    for (int c = 0; c < 512; ++c) {
        float w = __bfloat162float(wb[(size_t)c * 512]);
#pragma unroll
        for (int j = 0; j < 9; ++j)          // cells 0..8 past cell0 always in-bounds
            acc[j] = fmaf(w, pc[c * 50 + j], acc[j]);
    }
    float* Mp = M + ((size_t)(n * 512 + co) * 9 + tap) * 50 + cell0;
    for (int j = 0; j < nc; ++j) Mp[j] = acc[j];
}

// bilinear cell coefficients for branch with grid s x s at pixel (yy,xx) in 48x48
struct B4 { int c0, c1, c2, c3; float w0, w1, w2, w3; };
__device__ __forceinline__ B4 cell_interp(int yy, int xx, int s, int base) {
    int sm1 = s - 1;
    int yn = yy * sm1, xn = xx * sm1;
    int y0 = yn / 47, x0 = xn / 47;
    float wy = (float)(yn - y0 * 47) * (1.f / 47.f);
    float wx = (float)(xn - x0 * 47) * (1.f / 47.f);
    int y1 = min(y0 + 1, sm1), x1 = min(x0 + 1, sm1);
    B4 r;
    r.c0 = base + y0 * s + x0; r.c1 = base + y0 * s + x1;
    r.c2 = base + y1 * s + x0; r.c3 = base + y1 * s + x1;
    r.w0 = (1.f - wy) * (1.f - wx); r.w1 = (1.f - wy) * wx;
    r.w2 = wy * (1.f - wx);         r.w3 = wy * wx;
    return r;
}

// ---------------- x (fp32 [n,2048,48,48]) -> xtp (bf16 [n,50*50,2048], pad=0) ---
__global__ __launch_bounds__(256) void k_xtrans(const float* __restrict__ x,
                                                hbf* __restrict__ xtp) {
    __shared__ float tbuf[32][33];
    const int p0 = blockIdx.x * 32, c0 = blockIdx.y * 32, n = blockIdx.z;
    const int tx = threadIdx.x, ty = threadIdx.y;
#pragma unroll
    for (int i = 0; i < 4; ++i) {
        int ci = c0 + ty * 4 + i;
        tbuf[ty * 4 + i][tx] = x[((size_t)(n * 2048 + ci)) * 2304 + p0 + tx];
    }
    __syncthreads();
#pragma unroll
    for (int i = 0; i < 4; ++i) {
        int p = p0 + ty * 4 + i;
        int pp = (p / 48 + 1) * 50 + (p % 48) + 1;
        xtp[((size_t)(n * 2500 + pp)) * 2048 + c0 + tx] = __float2bfloat16(tbuf[tx][ty * 4 + i]);
    }
}

// ---------------- conv5 direct part: MFMA implicit GEMM, tap-fused, pipelined ---
__global__ __launch_bounds__(256) void k_conv5_mfma(const hbf* __restrict__ wt,
                                                    const hbf* __restrict__ xtp,
                                                    float* __restrict__ c5acc) {
    __shared__ hbf As[2][3][128 * 32];   // 2 x 24KB
    __shared__ hbf Bs[2][136 * 32];      // 2 x 8.5KB
    const int tid = threadIdx.x;
    const int l = tid & 63, w = tid >> 6;
    const int m0 = blockIdx.x * 128;
    const int P0 = blockIdx.y * 128;
    const int g  = blockIdx.z;               // tap row (dy = g-1)
    const int n_img = P0 / 2304;
    const int pbase = P0 - n_img * 2304;
    const int r0 = tid >> 2;
    const int swzk = ((tid & 3) ^ ((r0 >> 1) & 3)) * 8;

    const int pp0 = pbase + 2 * (pbase / 48) + 51;
    const ptrdiff_t browbase = (ptrdiff_t)n_img * 2500 + pp0 + (g - 1) * 50 - 1;

    const int wm = (w & 1) * 64, wn = (w >> 1) * 64;
    int jb[4];
#pragma unroll
    for (int tj = 0; tj < 4; ++tj) {
        int p = pbase + wn + tj * 16 + (l & 15);
        jb[tj] = p + 2 * (p / 48) + 51 - pp0;          // 0..133
    }
    const int slotA = ((l >> 4) ^ ((l >> 1) & 3)) * 8;

    f32x4 acc[4][4];
#pragma unroll
    for (int i = 0; i < 4; ++i)
#pragma unroll
        for (int j = 0; j < 4; ++j) acc[i][j] = {0.f, 0.f, 0.f, 0.f};

    const hbf* gA = wt + ((size_t)(g * 1536 + m0 + r0)) * 2048 + swzk;
    const hbf* gB = xtp + (size_t)(browbase + r0) * 2048 + swzk;

#define STAGE5(buf, k0) do {                                                       \
        hbf* ldsA_ = &As[buf][0][0] + w * 512;                                     \
        hbf* ldsB_ = &Bs[buf][0] + w * 512;                                        \
        _Pragma("unroll")                                                          \
        for (int t_ = 0; t_ < 3; ++t_) {                                           \
            GLDS(gA + (size_t)t_ * 512 * 2048 + (k0),             ldsA_ + t_ * 4096);      \
            GLDS(gA + (size_t)t_ * 512 * 2048 + 64 * 2048 + (k0), ldsA_ + t_ * 4096 + 2048); \
        }                                                                          \
        GLDS(gB + (k0),                      ldsB_);                               \
        GLDS(gB + (size_t)64 * 2048 + (k0),  ldsB_ + 2048);                        \
        if (tid < 32)                                                              \
            GLDS(gB + (size_t)128 * 2048 + (k0), &Bs[buf][0] + 4096);              \
    } while (0)

    STAGE5(0, 0);
    int cur = 0;
#pragma unroll 2
    for (int k0 = 0; k0 < 2048; k0 += 32) {
        __syncthreads();   // drains prev stage (issued one compute phase ago)
        if (k0 + 32 < 2048) STAGE5(cur ^ 1, k0 + 32);
#pragma unroll
        for (int t = 0; t < 3; ++t) {
            bf16x8 af[4], bfr[4];
#pragma unroll
            for (int ti = 0; ti < 4; ++ti)
                af[ti] = *(const bf16x8*)(&As[cur][t][(wm + ti * 16 + (l & 15)) * 32 + slotA]);
#pragma unroll
            for (int tj = 0; tj < 4; ++tj) {
                const int brow = jb[tj] + t;
                bfr[tj] = *(const bf16x8*)(&Bs[cur][0] + brow * 32 + (((l >> 4) ^ ((brow >> 1) & 3)) * 8));
            }
#pragma unroll
            for (int ti = 0; ti < 4; ++ti)
#pragma unroll
                for (int tj = 0; tj < 4; ++tj)
                    acc[ti][tj] = __builtin_amdgcn_mfma_f32_16x16x32_bf16(
                        af[ti], bfr[tj], acc[ti][tj], 0, 0, 0);
        }
        cur ^= 1;
    }
#undef STAGE5

#pragma unroll
    for (int ti = 0; ti < 4; ++ti) {
        const int mrow = wm + ti * 16 + (l >> 4) * 4;
#pragma unroll
        for (int tj = 0; tj < 4; ++tj) {
            const int p = pbase + wn + tj * 16 + (l & 15);
            float* dst = c5acc + ((size_t)(n_img * 512 + m0 + mrow)) * 2304 + p;
#pragma unroll
            for (int r = 0; r < 4; ++r)
                atomicAdd(dst + (size_t)r * 2304, acc[ti][tj][r]);
        }
    }
}

// ---------------- epilogue: + psp(M)-part, BN, ReLU -> c5out bf16 ---------------
__global__ __launch_bounds__(256) void k_bnrelu_psp(const float* __restrict__ c5acc,
                                                    const float* __restrict__ M,
                                                    const float* __restrict__ bnp,
                                                    hbf* __restrict__ c5out) {
    const int co = blockIdx.x, n = blockIdx.y;
    __shared__ float Ms[450];
    const float* Mrow = M + ((size_t)(n * 512 + co)) * 450;
    for (int i = threadIdx.x; i < 450; i += 256) Ms[i] = Mrow[i];
    __syncthreads();
    float s, t; bn_coef(bnp, 512, co, s, t);
    const size_t base = ((size_t)(n * 512 + co)) * 2304;
#pragma unroll
    for (int i = 0; i < 9; ++i) {
        int p = threadIdx.x + i * 256;
        int y = p / 48, x = p % 48;
        float a = c5acc[base + p];
#pragma unroll
        for (int ky = 0; ky < 3; ++ky) {
            int yy = y + ky - 1;
            if (yy < 0 || yy > 47) continue;
#pragma unroll
            for (int kx = 0; kx < 3; ++kx) {
                int xx = x + kx - 1;
                if (xx < 0 || xx > 47) continue;
                const float* Mp = Ms + (ky * 3 + kx) * 50;
                float sa = Mp[0];
                B4 b2 = cell_interp(yy, xx, 2, 1);
                B4 b3 = cell_interp(yy, xx, 3, 5);
                B4 b6 = cell_interp(yy, xx, 6, 14);
                sa = fmaf(b2.w0, Mp[b2.c0], sa); sa = fmaf(b2.w1, Mp[b2.c1], sa);
                sa = fmaf(b2.w2, Mp[b2.c2], sa); sa = fmaf(b2.w3, Mp[b2.c3], sa);
                sa = fmaf(b3.w0, Mp[b3.c0], sa); sa = fmaf(b3.w1, Mp[b3.c1], sa);
                sa = fmaf(b3.w2, Mp[b3.c2], sa); sa = fmaf(b3.w3, Mp[b3.c3], sa);
                sa = fmaf(b6.w0, Mp[b6.c0], sa); sa = fmaf(b6.w1, Mp[b6.c1], sa);
                sa = fmaf(b6.w2, Mp[b6.c2], sa); sa = fmaf(b6.w3, Mp[b6.c3], sa);
                a += sa;
            }
        }
        c5out[base + p] = __float2bfloat16(fmaxf(fmaf(a, s, t), 0.f));
    }
}

// ---------------- conv6 at 48x48 (512->59, no bias), c5out bf16 -----------------
// R4 form: 1416 blocks (16 waves/CU) — high TLP hides the strided 2B loads.
__global__ __launch_bounds__(192) void k_conv6s(const hbf* __restrict__ c5o,
                                                const float* __restrict__ w,
                                                float* __restrict__ out) {
    const int x = threadIdx.x;
    const int y = blockIdx.y * 4 + threadIdx.y;
    const int n = blockIdx.z;
    const int co = blockIdx.x;
    const int p = y * 48 + x;
    const hbf* ip = c5o + (size_t)n * 512 * 2304 + p;
    const float* wr = w + (size_t)co * 512;
    float a0 = 0.f, a1 = 0.f, a2 = 0.f, a3 = 0.f;
    for (int ci = 0; ci < 512; ci += 4) {
        a0 = fmaf(__bfloat162float(ip[(size_t)ci * 2304]),       wr[ci],     a0);
        a1 = fmaf(__bfloat162float(ip[(size_t)(ci + 1) * 2304]), wr[ci + 1], a1);
        a2 = fmaf(__bfloat162float(ip[(size_t)(ci + 2) * 2304]), wr[ci + 2], a2);
        a3 = fmaf(__bfloat162float(ip[(size_t)(ci + 3) * 2304]), wr[ci + 3], a3);
    }
    out[((size_t)n * 59 + co) * 2304 + p] = (a0 + a1) + (a2 + a3);
}

// ---------------- final: out = bias + sum_k att[k]*up96(c6s)[tap_k] -------------
__global__ void k_final(const float* __restrict__ att, const float* __restrict__ c6s,
                        const float* __restrict__ bias, float* __restrict__ out) {
    int idx = blockIdx.x * blockDim.x + threadIdx.x;  // 2*59*9216
    int p = idx % 9216;
    int nc = idx / 9216;
    int cls = nc % 59, n = nc / 59;
    int y = p / 96, x = p % 96;
    const float* ar = att + ((size_t)n * 9216 + p) * 9;
    const float* cp = c6s + (size_t)nc * 2304;
    int xs0[3], xs1[3], ys0[3], ys1[3];
    float fx[3], fy[3];
#pragma unroll
    for (int d = 0; d < 3; ++d) {
        int xx = x + 2 * d - 2;
        if (xx >= 0 && xx < 96) {
            int xn = xx * 47, x0 = xn / 95;
            xs0[d] = x0; xs1[d] = min(x0 + 1, 47);
            fx[d] = (float)(xn - x0 * 95) * (1.f / 95.f);
        } else { xs0[d] = -1; xs1[d] = 0; fx[d] = 0.f; }
        int yy = y + 2 * d - 2;
        if (yy >= 0 && yy < 96) {
            int yn = yy * 47, y0 = yn / 95;
            ys0[d] = y0; ys1[d] = min(y0 + 1, 47);
            fy[d] = (float)(yn - y0 * 95) * (1.f / 95.f);
        } else { ys0[d] = -1; ys1[d] = 0; fy[d] = 0.f; }
    }
    float a = bias[cls];
#pragma unroll
    for (int ky = 0; ky < 3; ++ky) {
        if (ys0[ky] < 0) continue;
        const float* r0 = cp + ys0[ky] * 48;
        const float* r1 = cp + ys1[ky] * 48;
        float wy = fy[ky];
#pragma unroll
        for (int kx = 0; kx < 3; ++kx) {
            if (xs0[kx] < 0) continue;
            float wx = fx[kx];
            float v0 = r0[xs0[kx]] * (1.f - wx) + r0[xs1[kx]] * wx;
            float v1 = r1[xs0[kx]] * (1.f - wx) + r1[xs1[kx]] * wx;
            a = fmaf(ar[ky * 3 + kx], v0 * (1.f - wy) + v1 * wy, a);
        }
    }
    out[idx] = a;
}

extern "C" void kernel_launch(void* const* d_in, const int* in_sizes, int n_in,
                              void* d_out, int out_size, void* d_ws, size_t ws_size,
                              hipStream_t stream) {
    const float* c1    = (const float*)d_in[0];
    const float* c2    = (const float*)d_in[1];
    const float* xin   = (const float*)d_in[2];
    const float* w_r1  = (const float*)d_in[3];
    const float* bn_r1 = (const float*)d_in[4];
    const float* w_r2  = (const float*)d_in[5];
    const float* bn_r2 = (const float*)d_in[6];
    const float* w_r3  = (const float*)d_in[7];
    const float* bn_r3 = (const float*)d_in[8];
    const float* w_p1  = (const float*)d_in[9];
    const float* bn_p1 = (const float*)d_in[10];
    const float* w_p2  = (const float*)d_in[11];
    const float* bn_p2 = (const float*)d_in[12];
    const float* w_p3  = (const float*)d_in[13];
    const float* bn_p3 = (const float*)d_in[14];
    const float* w_p4  = (const float*)d_in[15];
    const float* bn_p4 = (const float*)d_in[16];
    const float* w_c5  = (const float*)d_in[17];
    const float* bn_c5 = (const float*)d_in[18];
    const float* w_c6  = (const float*)d_in[19];
    const float* b_c6  = (const float*)d_in[20];
    float* out = (float*)d_out;
    (void)in_sizes; (void)n_in; (void)out_size; (void)ws_size;

    char* base = (char*)d_ws;
    float* att = (float*)base;                    // 663,552 B
    char*  A   = base + 663552;
    // ---- phase 1 layout (region A) ----
    hbf*   c1t   = (hbf*)A;                       // 10,240,000
    hbf*   r1t   = (hbf*)(A + 10240000);          //  2,560,000
    float* r1acc = (float*)(A + 12800000);        //  4,718,592
    float* qacc  = (float*)(A + 17518592);        //  4,718,592
    float* c2acc = (float*)(A + 22237184);        //  1,179,648  (fill ends 23,416,832)
    float* c2r   = (float*)(A + 28135424);        //  4,718,592
    hbf*   wr1t  = (hbf*)(A + 32854016);          //    294,912
    hbf*   wr2t  = (hbf*)(A + 33148928);          //     73,728  (ends 33,222,656)
    // ---- phase 2 early (region A): wpsp aliased under xtp, consumed pre-fill ----
    hbf*   wpsp   = (hbf*)A;                      // 18,874,368 (< xtp's 20,480,000)
    float* pooled = (float*)(A + 48791552);       //    819,200  (now [n][50][2048])
    float* pconv  = (float*)(A + 49610752);       //    204,800
    float* M      = (float*)(A + 49815552);       //  1,843,200  (ends 51,658,752)
    // ---- phase 2 main (region A, reuses wpsp space) ----
    hbf*   xtp    = (hbf*)A;                      // 20,480,000
    float* c5acc  = (float*)(A + 20480000);       //  9,437,184
    hbf*   wt     = (hbf*)(A + 29917184);         // 18,874,368
    // ---- phase 2b (after conv5), aliased over xtp ----
    hbf*   c5out = (hbf*)A;                       //  4,718,592
    float* c6s   = (float*)(A + 4718592);         //  1,087,488
    // total ws: 663,552 + 51,658,752 = 52,322,304 B (unchanged)

    // ---- phase 1: attention branch ----
    k_fill0<<<dim3(22868), 256, 0, stream>>>((uint32_t*)A, 5854208);
    k_c1trans<<<dim3(288, 8, 2), dim3(32, 8), 0, stream>>>(c1, c1t);
    k_wsmall<<<dim3(80), 256, 0, stream>>>(w_r1, wr1t, w_r2, wr2t);
    k_dconv_mfma<256><<<dim3(144, 3), 256, 0, stream>>>(wr1t, c1t, r1acc);
    k_ep_r1<<<dim3(288), 256, 0, stream>>>(r1acc, bn_r1, r1t);
    k_dconv_mfma<64><<<dim3(144, 3), 256, 0, stream>>>(wr2t, r1t, qacc);
    k_conv1x1_c2<<<dim3(8, 12, 8), dim3(48, 4), 0, stream>>>(c2, w_r3, c2acc);
    k_up96<<<dim3(2 * 64 * 9216 / 256), 256, 0, stream>>>(c2acc, c2r, 64, bn_r3);
    k_attention<<<dim3(288), 256, 0, stream>>>(qacc, bn_r2, c2r, att);
    // ---- phase 2: psp branch ----
    k_pool<<<dim3(4096), 64, 0, stream>>>(xin, pooled);
    k_pconv2<<<dim3(512, 2), 64, 0, stream>>>(pooled, w_p1, bn_p1, w_p2, bn_p2,
                                              w_p3, bn_p3, w_p4, bn_p4, pconv);
    k_wtrans_all<<<dim3(4352), 256, 0, stream>>>(w_c5, wt, wpsp);
    k_computeM2<<<dim3(8, 9, 14), 64, 0, stream>>>(wpsp, pconv, M);
    k_fill0<<<dim3(29216), 256, 0, stream>>>((uint32_t*)xtp, 7479296);
    k_xtrans<<<dim3(72, 64, 2), dim3(32, 8), 0, stream>>>(xin, xtp);
    k_conv5_mfma<<<dim3(4, 36, 3), 256, 0, stream>>>(wt, xtp, c5acc);
    k_bnrelu_psp<<<dim3(512, 2), 256, 0, stream>>>(c5acc, M, bn_c5, c5out);
    // classifier (conv6 commuted before upsample) + attention aggregation
    k_conv6s<<<dim3(59, 12, 2), dim3(48, 4), 0, stream>>>(c5out, w_c6, c6s);
    k_final<<<dim3(2 * 59 * 9216 / 256), 256, 0, stream>>>(att, c6s, b_c6, out);
}

// Round 7
// 653.271 us; speedup vs baseline: 1.0478x; 1.0128x over previous
//
#include <hip/hip_runtime.h>
#include <hip/hip_bf16.h>
#include <cstddef>
#include <cstdint>

typedef __hip_bfloat16 hbf;
typedef __bf16 bf16x8 __attribute__((ext_vector_type(8)));
typedef float f32x4 __attribute__((ext_vector_type(4)));

#define GLDS(gp, lp) __builtin_amdgcn_global_load_lds( \
    (const __attribute__((address_space(1))) void*)(gp), \
    (__attribute__((address_space(3))) void*)(lp), 16, 0, 0)

// bn: y = x*s + t, s = g*rsqrt(v+eps), t = b - m*s
__device__ __forceinline__ void bn_coef(const float* __restrict__ p, int C, int c,
                                        float& s, float& t) {
    float g = p[c];
    float b = p[C + c];
    float m = p[2 * C + c];
    float v = p[3 * C + c];
    s = g * rsqrtf(v + 1e-5f);
    t = b - m * s;
}

// ---------------- zero-fill (dwords) --------------------------------------------
__global__ void k_fill0(uint32_t* __restrict__ p, int n) {
    int i = blockIdx.x * blockDim.x + threadIdx.x;
    if (i < n) p[i] = 0u;
}

// ---------------- c1 fp32 [2,256,96,96] -> c1t bf16 [n][100*100][256], pad=2 ----
__global__ __launch_bounds__(256) void k_c1trans(const float* __restrict__ x,
                                                 hbf* __restrict__ c1t) {
    __shared__ float tbuf[32][33];
    const int p0 = blockIdx.x * 32, c0 = blockIdx.y * 32, n = blockIdx.z;
    const int tx = threadIdx.x, ty = threadIdx.y;
#pragma unroll
    for (int i = 0; i < 4; ++i) {
        int ci = c0 + ty * 4 + i;
        tbuf[ty * 4 + i][tx] = x[((size_t)(n * 256 + ci)) * 9216 + p0 + tx];
    }
    __syncthreads();
#pragma unroll
    for (int i = 0; i < 4; ++i) {
        int p = p0 + ty * 4 + i;
        int pp = (p / 96 + 2) * 100 + (p % 96) + 2;
        c1t[((size_t)(n * 10000 + pp)) * 256 + c0 + tx] = __float2bfloat16(tbuf[tx][ty * 4 + i]);
    }
}

// ---------------- both small conv weights -> [tap][64][CI] bf16, one launch -----
__global__ __launch_bounds__(256) void k_wsmall(const float* __restrict__ w1,
                                                hbf* __restrict__ wt1,
                                                const float* __restrict__ w2,
                                                hbf* __restrict__ wt2) {
    int b = blockIdx.x;
    if (b < 64) {           // w_r1: [64][256][3][3]
        int idx = b * 256 + threadIdx.x;
        int co = idx >> 8, ci = idx & 255;
        const float* s = w1 + ((size_t)(co * 256 + ci)) * 9;
#pragma unroll
        for (int tap = 0; tap < 9; ++tap)
            wt1[((size_t)(tap * 64 + co)) * 256 + ci] = __float2bfloat16(s[tap]);
    } else {                // w_r2: [64][64][3][3]
        int idx = (b - 64) * 256 + threadIdx.x;
        int co = idx >> 6, ci = idx & 63;
        const float* s = w2 + ((size_t)(co * 64 + ci)) * 9;
#pragma unroll
        for (int tap = 0; tap < 9; ++tap)
            wt2[((size_t)(tap * 64 + co)) * 64 + ci] = __float2bfloat16(s[tap]);
    }
}

// ---------------- dilated 3x3 conv (d=2) MFMA, ALL 9 taps per block -------------
// g-loop inside: single writer per output -> plain stores (no atomics, no
// zero-fill of the accumulator), 3x the k-steps per block (prologue amortized).
template <int CI>
__global__ __launch_bounds__(256) void k_dconv_mfma(const hbf* __restrict__ wt,
                                                    const hbf* __restrict__ it,
                                                    float* __restrict__ accout) {
    constexpr int KS = CI / 32;
    __shared__ hbf As[2][3][64 * 32];   // per-tap weights [64 co][32 k]
    __shared__ hbf Bs[2][72 * 32];      // union of pixel rows (tap col-shifts -2,0,+2)
    const int tid = threadIdx.x;
    const int l = tid & 63, w = tid >> 6;
    const int P0 = blockIdx.x * 64;
    const int r0 = tid >> 2;
    const int swzk = ((tid & 3) ^ ((r0 >> 1) & 3)) * 8;

    const int n_i = P0 / 9216;
    const int pl0 = P0 - n_i * 9216;
    const int pp0 = (pl0 / 96 + 2) * 100 + (pl0 % 96) + 2;
    const ptrdiff_t bb0 = (ptrdiff_t)n_i * 10000 + pp0 - 202;  // + g*200 per tap row

    const int wn = w * 16;
    const int pl_lane = pl0 + wn + (l & 15);
    const int jb = ((pl_lane / 96 + 2) * 100 + (pl_lane % 96) + 2) - pp0;  // 0..67
    const int slotA = ((l >> 4) ^ ((l >> 1) & 3)) * 8;

    f32x4 acc[4];
#pragma unroll
    for (int i = 0; i < 4; ++i) acc[i] = {0.f, 0.f, 0.f, 0.f};

#define STAGE_D(buf, gg, k0) do {                                              \
        const hbf* gA_ = wt + ((size_t)((gg) * 192 + r0)) * CI + swzk;         \
        const hbf* gB_ = it + (size_t)(bb0 + (gg) * 200 + r0) * CI + swzk;     \
        hbf* ldsA_ = &As[buf][0][0] + w * 512;                                 \
        hbf* ldsB_ = &Bs[buf][0] + w * 512;                                    \
        _Pragma("unroll")                                                      \
        for (int t_ = 0; t_ < 3; ++t_)                                         \
            GLDS(gA_ + (size_t)t_ * 64 * CI + (k0), ldsA_ + t_ * 2048);        \
        GLDS(gB_ + (k0), ldsB_);                                               \
        if (tid < 32)                                                          \
            GLDS(gB_ + (size_t)64 * CI + (k0), &Bs[buf][0] + 2048);            \
    } while (0)

    STAGE_D(0, 0, 0);
    int cur = 0;
    for (int g = 0; g < 3; ++g) {
#pragma unroll
        for (int ks = 0; ks < KS; ++ks) {
            __syncthreads();   // drains prev stage (issued one compute phase ago)
            int ns = g * KS + ks + 1;
            if (ns < 3 * KS) STAGE_D(cur ^ 1, ns / KS, (ns % KS) * 32);
#pragma unroll
            for (int t = 0; t < 3; ++t) {
                const int brow = jb + 2 * t;
                bf16x8 bfr = *(const bf16x8*)(&Bs[cur][0] + brow * 32 + (((l >> 4) ^ ((brow >> 1) & 3)) * 8));
#pragma unroll
                for (int ti = 0; ti < 4; ++ti) {
                    bf16x8 af = *(const bf16x8*)(&As[cur][t][(ti * 16 + (l & 15)) * 32 + slotA]);
                    acc[ti] = __builtin_amdgcn_mfma_f32_16x16x32_bf16(af, bfr, acc[ti], 0, 0, 0);
                }
            }
            cur ^= 1;
        }
    }
#undef STAGE_D

    const int px = P0 + wn + (l & 15);
    const int n2 = px / 9216, pl2 = px % 9216;
#pragma unroll
    for (int ti = 0; ti < 4; ++ti) {
        const int mrow = ti * 16 + (l >> 4) * 4;
        float* dst = accout + ((size_t)(n2 * 64 + mrow)) * 9216 + pl2;
#pragma unroll
        for (int r = 0; r < 4; ++r)
            dst[(size_t)r * 9216] = acc[ti][r];
    }
}

// ---------------- ep_r1: BN+ReLU(r1acc) -> r1t bf16 padded-transposed -----------
__global__ __launch_bounds__(256) void k_ep_r1(const float* __restrict__ acc,
                                               const float* __restrict__ bnp,
                                               hbf* __restrict__ r1t) {
    const int q = threadIdx.x >> 6;         // channel quarter
    const int ln = threadIdx.x & 63;
    const int pi = blockIdx.x * 64 + ln;    // 0..18431
    const int n = pi / 9216, pl = pi % 9216;
    const int pp = (pl / 96 + 2) * 100 + (pl % 96) + 2;
    hbf* dst = r1t + ((size_t)(n * 10000 + pp)) * 64 + q * 16;
    const float* src = acc + (size_t)(n * 64 + q * 16) * 9216 + pl;
#pragma unroll
    for (int i = 0; i < 16; ++i) {
        float s, t; bn_coef(bnp, 64, q * 16 + i, s, t);
        dst[i] = __float2bfloat16(fmaxf(fmaf(src[(size_t)i * 9216], s, t), 0.f));
    }
}

// ---------------- qt: BN+ReLU(qacc) -> q_t fp32 [n][9216 px][64 ch] -------------
__global__ __launch_bounds__(256) void k_qt(const float* __restrict__ acc,
                                            const float* __restrict__ bnp,
                                            float* __restrict__ qt) {
    __shared__ float tbuf[32][33];
    const int p0 = blockIdx.x * 32, c0 = blockIdx.y * 32, n = blockIdx.z;
    const int tx = threadIdx.x, ty = threadIdx.y;
#pragma unroll
    for (int i = 0; i < 4; ++i) {
        int ci = c0 + ty * 4 + i;
        tbuf[ty * 4 + i][tx] = acc[((size_t)(n * 64 + ci)) * 9216 + p0 + tx];
    }
    __syncthreads();
    float s, t; bn_coef(bnp, 64, c0 + tx, s, t);
#pragma unroll
    for (int i = 0; i < 4; ++i) {
        int p = p0 + ty * 4 + i;
        qt[((size_t)(n * 9216 + p)) * 64 + c0 + tx] =
            fmaxf(fmaf(tbuf[tx][ty * 4 + i], s, t), 0.f);
    }
}

// ---------------- kt: upsample48->96 + BN + ReLU -> k_t fp32 [n][9216][64] ------
__global__ __launch_bounds__(256) void k_kt(const float* __restrict__ c2acc,
                                            const float* __restrict__ bnp,
                                            float* __restrict__ kt) {
    __shared__ float tbuf[32][33];
    const int p0 = blockIdx.x * 32, c0 = blockIdx.y * 32, n = blockIdx.z;
    const int tx = threadIdx.x, ty = threadIdx.y;
    const int p = p0 + tx;
    const int y = p / 96, x = p % 96;
    int yn = y * 47, xn = x * 47;
    int y0 = yn / 95, x0 = xn / 95;
    float wy = (float)(yn - y0 * 95) * (1.f / 95.f);
    float wx = (float)(xn - x0 * 95) * (1.f / 95.f);
    int y1 = min(y0 + 1, 47), x1 = min(x0 + 1, 47);
#pragma unroll
    for (int i = 0; i < 4; ++i) {
        int c = c0 + ty * 4 + i;
        const float* sp = c2acc + ((size_t)(n * 64 + c)) * 2304;
        float v00 = sp[y0 * 48 + x0], v01 = sp[y0 * 48 + x1];
        float v10 = sp[y1 * 48 + x0], v11 = sp[y1 * 48 + x1];
        tbuf[ty * 4 + i][tx] = (v00 * (1.f - wx) + v01 * wx) * (1.f - wy)
                             + (v10 * (1.f - wx) + v11 * wx) * wy;
    }
    __syncthreads();
    float s, t; bn_coef(bnp, 64, c0 + tx, s, t);
#pragma unroll
    for (int i = 0; i < 4; ++i) {
        int pw = p0 + ty * 4 + i;
        kt[((size_t)(n * 9216 + pw)) * 64 + c0 + tx] =
            fmaxf(fmaf(tbuf[tx][ty * 4 + i], s, t), 0.f);
    }
}

// ---------------- 1x1 conv on c2 (512->64), 16 co/block, ci split 4-ways --------
__global__ __launch_bounds__(192) void k_conv1x1_c2(const float* __restrict__ c2,
                                                    const float* __restrict__ w,
                                                    float* __restrict__ outacc) {
    const int x = threadIdx.x;
    const int y = blockIdx.y * 4 + threadIdx.y;
    const int n = blockIdx.z >> 2;
    const int ci0 = (blockIdx.z & 3) * 128;
    const int cg = blockIdx.x;
    const int p = y * 48 + x;
    float acc[16];
#pragma unroll
    for (int j = 0; j < 16; ++j) acc[j] = 0.f;
    for (int ci = ci0; ci < ci0 + 128; ++ci) {
        float iv = c2[(size_t)(n * 512 + ci) * 2304 + p];
#pragma unroll
        for (int j = 0; j < 16; ++j)
            acc[j] = fmaf(iv, w[(size_t)(cg * 16 + j) * 512 + ci], acc[j]);
    }
#pragma unroll
    for (int j = 0; j < 16; ++j)
        atomicAdd(&outacc[(size_t)(n * 64 + cg * 16 + j) * 2304 + p], acc[j]);
}

// ---------------- energy + softmax -> att [n,9216,9], px-major q/k --------------
// Per-thread reads are contiguous 64B f32x4 segments (was 36KB-stride column
// gathers through planar layout: 144 cache lines/thread -> ~170MB effective).
__global__ __launch_bounds__(256) void k_attention(const float* __restrict__ qt,
                                                   const float* __restrict__ kt,
                                                   float* __restrict__ att) {
    const int wv = threadIdx.x >> 6;        // channel quarter 0..3
    const int ln = threadIdx.x & 63;
    const int p_abs = blockIdx.x * 64 + ln; // 0..18431
    const int n = p_abs / 9216, p = p_abs % 9216;
    const int y = p / 96, x = p % 96;
    float qv[16];
    {
        const f32x4* qr = (const f32x4*)(qt + (size_t)p_abs * 64 + wv * 16);
#pragma unroll
        for (int j = 0; j < 4; ++j) {
            f32x4 v = qr[j];
            qv[4 * j + 0] = v[0]; qv[4 * j + 1] = v[1];
            qv[4 * j + 2] = v[2]; qv[4 * j + 3] = v[3];
        }
    }
    const float* kb = kt + (size_t)n * 9216 * 64 + wv * 16;
    float e[9];
#pragma unroll
    for (int ky = 0; ky < 3; ++ky)
#pragma unroll
        for (int kx = 0; kx < 3; ++kx) {
            int yy = y + 2 * ky - 2, xx = x + 2 * kx - 2;
            float s = 0.f;
            if (yy >= 0 && yy < 96 && xx >= 0 && xx < 96) {
                const f32x4* kr = (const f32x4*)(kb + (size_t)(yy * 96 + xx) * 64);
#pragma unroll
                for (int j = 0; j < 4; ++j) {
                    f32x4 kv = kr[j];
                    s = fmaf(qv[4 * j + 0], kv[0], s);
                    s = fmaf(qv[4 * j + 1], kv[1], s);
                    s = fmaf(qv[4 * j + 2], kv[2], s);
                    s = fmaf(qv[4 * j + 3], kv[3], s);
                }
            }
            e[ky * 3 + kx] = s;
        }
    __shared__ float pe[9][4][64];
#pragma unroll
    for (int k = 0; k < 9; ++k) pe[k][wv][ln] = e[k];
    __syncthreads();
    if (threadIdx.x < 64) {
        float ee[9];
#pragma unroll
        for (int k = 0; k < 9; ++k)
            ee[k] = (pe[k][0][ln] + pe[k][1][ln]) + (pe[k][2][ln] + pe[k][3][ln]);
        float m = ee[0];
#pragma unroll
        for (int k = 1; k < 9; ++k) m = fmaxf(m, ee[k]);
        float sum = 0.f;
#pragma unroll
        for (int k = 0; k < 9; ++k) { ee[k] = __expf(ee[k] - m); sum += ee[k]; }
        float inv = 1.f / sum;
        float* ap = att + (size_t)p_abs * 9;
#pragma unroll
        for (int k = 0; k < 9; ++k) ap[k] = ee[k] * inv;
    }
}

// ---------------- adaptive avg pools s=1,2,3,6 -> pooled_t [n,50,2048] ----------
__global__ __launch_bounds__(64) void k_pool(const float* __restrict__ xin,
                                             float* __restrict__ pooled) {
    int b = blockIdx.x;            // n*2048+c
    int t = threadIdx.x;
    __shared__ float cells[50];
    if (t < 50) cells[t] = 0.f;
    __syncthreads();
    float rs = 0.f;
    if (t < 48) {
        const f32x4* rowv = (const f32x4*)(xin + (size_t)b * 2304 + t * 48);
        float s6[6];
#pragma unroll
        for (int j = 0; j < 6; ++j) {
            f32x4 u = rowv[2 * j], v = rowv[2 * j + 1];
            s6[j] = ((u[0] + u[1]) + (u[2] + u[3])) + ((v[0] + v[1]) + (v[2] + v[3]));
        }
        float s3a = s6[0] + s6[1], s3b = s6[2] + s6[3], s3c = s6[4] + s6[5];
        float s2a = s3a + s6[2], s2b = s6[3] + s3c;
        rs = s2a + s2b;
        int r6 = t >> 3, r3 = t >> 4, r2 = t / 24;
        atomicAdd(&cells[14 + r6 * 6 + 0], s6[0]);
        atomicAdd(&cells[14 + r6 * 6 + 1], s6[1]);
        atomicAdd(&cells[14 + r6 * 6 + 2], s6[2]);
        atomicAdd(&cells[14 + r6 * 6 + 3], s6[3]);
        atomicAdd(&cells[14 + r6 * 6 + 4], s6[4]);
        atomicAdd(&cells[14 + r6 * 6 + 5], s6[5]);
        atomicAdd(&cells[5 + r3 * 3 + 0], s3a);
        atomicAdd(&cells[5 + r3 * 3 + 1], s3b);
        atomicAdd(&cells[5 + r3 * 3 + 2], s3c);
        atomicAdd(&cells[1 + r2 * 2 + 0], s2a);
        atomicAdd(&cells[1 + r2 * 2 + 1], s2b);
    }
#pragma unroll
    for (int off = 32; off > 0; off >>= 1) rs += __shfl_down(rs, off);
    if (t == 0) atomicAdd(&cells[0], rs);
    __syncthreads();
    if (t < 50) {
        float inv = (t == 0) ? (1.f / 2304.f)
                  : (t < 5)  ? (1.f / 576.f)
                  : (t < 14) ? (1.f / 256.f)
                             : (1.f / 64.f);
        pooled[((size_t)(b >> 11) * 50 + t) * 2048 + (b & 2047)] = cells[t] * inv;
    }
}

// ---------------- pconv2: 1x1 conv 2048->512 per cell + BN + ReLU ---------------
__global__ __launch_bounds__(64) void k_pconv2(const float* __restrict__ pooled_t,
        const float* __restrict__ wp1, const float* __restrict__ bn1,
        const float* __restrict__ wp2, const float* __restrict__ bn2,
        const float* __restrict__ wp3, const float* __restrict__ bn3,
        const float* __restrict__ wp4, const float* __restrict__ bn4,
        float* __restrict__ pconv) {
    const int co = blockIdx.x, n = blockIdx.y;
    const int t = threadIdx.x;
    const int cell = (t < 50) ? t : 49;
    const float* w; const float* bnp;
    if (cell == 0)      { w = wp1; bnp = bn1; }
    else if (cell < 5)  { w = wp2; bnp = bn2; }
    else if (cell < 14) { w = wp3; bnp = bn3; }
    else                { w = wp4; bnp = bn4; }
    const float* pin = pooled_t + ((size_t)n * 50 + cell) * 2048;
    const float* wr = w + (size_t)co * 2048;
    float a0 = 0.f, a1 = 0.f, a2 = 0.f, a3 = 0.f;
    for (int c = 0; c < 2048; c += 4) {
        f32x4 v = *(const f32x4*)(pin + c);
        f32x4 ww = *(const f32x4*)(wr + c);
        a0 = fmaf(v[0], ww[0], a0);
        a1 = fmaf(v[1], ww[1], a1);
        a2 = fmaf(v[2], ww[2], a2);
        a3 = fmaf(v[3], ww[3], a3);
    }
    float a = (a0 + a1) + (a2 + a3);
    float s, tt; bn_coef(bnp, 512, co, s, tt);
    if (t < 50)
        pconv[((size_t)n * 512 + co) * 50 + cell] = fmaxf(fmaf(a, s, tt), 0.f);
}

// ---------------- w_c5 -> wt (ci<2048) AND wpsp (ci>=2048), one launch ----------
__global__ __launch_bounds__(256) void k_wtrans_all(const float* __restrict__ w5,
                                                    hbf* __restrict__ wt,
                                                    hbf* __restrict__ wpsp) {
    int b = blockIdx.x;
    if (b < 4096) {       // wt: [tap][512 co][2048 ci]
        int idx = b * 256 + threadIdx.x;   // 512*2048
        int co = idx >> 11, ci = idx & 2047;
        const float* s = w5 + ((size_t)co * 4096 + ci) * 9;
#pragma unroll
        for (int tap = 0; tap < 9; ++tap)
            wt[((size_t)(tap * 512 + co)) * 2048 + ci] = __float2bfloat16(s[tap]);
    } else {              // wpsp: [tap][4 b][512 c][512 co]
        int r = b - 4096;                   // 0..255, decode (x=8, y=4, z=8)
        const int co = (r & 7) * 64 + (threadIdx.x & 63);
        const int bb = (r >> 3) & 3;
        const int c0 = (r >> 5) * 64 + (threadIdx.x >> 6) * 16;
        for (int i = 0; i < 16; ++i) {
            int c = c0 + i;
            const float* s = w5 + ((size_t)co * 4096 + 2048 + bb * 512 + c) * 9;
#pragma unroll
            for (int tap = 0; tap < 9; ++tap)
                wpsp[(((size_t)(tap * 4 + bb) * 512) + c) * 512 + co] = __float2bfloat16(s[tap]);
        }
    }
}

// ---------------- computeM2: M[n,co,tap,cell] via coalesced bf16 weights --------
__global__ __launch_bounds__(64) void k_computeM2(const hbf* __restrict__ wpsp,
                                                  const float* __restrict__ pconv,
                                                  float* __restrict__ M) {
    const int cog = blockIdx.x, tap = blockIdx.y;
    const int n = blockIdx.z / 7, chunk = blockIdx.z % 7;
    const int cell0_t[7] = {0, 1, 5, 14, 23, 32, 41};
    const int ncell_t[7] = {1, 4, 9, 9, 9, 9, 9};
    const int btab[7]    = {0, 1, 2, 3, 3, 3, 3};
    const int cell0 = cell0_t[chunk], nc = ncell_t[chunk], b = btab[chunk];
    const int co = cog * 64 + threadIdx.x;
    const hbf* wb = wpsp + ((size_t)(tap * 4 + b) * 512) * 512 + co;
    const float* pc = pconv + (size_t)n * 512 * 50 + cell0;
    float acc[9];
#pragma unroll
    for (int j = 0; j < 9; ++j) acc[j] = 0.f;
    for (int c = 0; c < 512; ++c) {
        float w = __bfloat162float(wb[(size_t)c * 512]);
#pragma unroll
        for (int j = 0; j < 9; ++j)          // cells 0..8 past cell0 always in-bounds
            acc[j] = fmaf(w, pc[c * 50 + j], acc[j]);
    }
    float* Mp = M + ((size_t)(n * 512 + co) * 9 + tap) * 50 + cell0;
    for (int j = 0; j < nc; ++j) Mp[j] = acc[j];
}

// bilinear cell coefficients for branch with grid s x s at pixel (yy,xx) in 48x48
struct B4 { int c0, c1, c2, c3; float w0, w1, w2, w3; };
__device__ __forceinline__ B4 cell_interp(int yy, int xx, int s, int base) {
    int sm1 = s - 1;
    int yn = yy * sm1, xn = xx * sm1;
    int y0 = yn / 47, x0 = xn / 47;
    float wy = (float)(yn - y0 * 47) * (1.f / 47.f);
    float wx = (float)(xn - x0 * 47) * (1.f / 47.f);
    int y1 = min(y0 + 1, sm1), x1 = min(x0 + 1, sm1);
    B4 r;
    r.c0 = base + y0 * s + x0; r.c1 = base + y0 * s + x1;
    r.c2 = base + y1 * s + x0; r.c3 = base + y1 * s + x1;
    r.w0 = (1.f - wy) * (1.f - wx); r.w1 = (1.f - wy) * wx;
    r.w2 = wy * (1.f - wx);         r.w3 = wy * wx;
    return r;
}

// ---------------- x (fp32 [n,2048,48,48]) -> xtp (bf16 [n,50*50,2048], pad=0) ---
__global__ __launch_bounds__(256) void k_xtrans(const float* __restrict__ x,
                                                hbf* __restrict__ xtp) {
    __shared__ float tbuf[32][33];
    const int p0 = blockIdx.x * 32, c0 = blockIdx.y * 32, n = blockIdx.z;
    const int tx = threadIdx.x, ty = threadIdx.y;
#pragma unroll
    for (int i = 0; i < 4; ++i) {
        int ci = c0 + ty * 4 + i;
        tbuf[ty * 4 + i][tx] = x[((size_t)(n * 2048 + ci)) * 2304 + p0 + tx];
    }
    __syncthreads();
#pragma unroll
    for (int i = 0; i < 4; ++i) {
        int p = p0 + ty * 4 + i;
        int pp = (p / 48 + 1) * 50 + (p % 48) + 1;
        xtp[((size_t)(n * 2500 + pp)) * 2048 + c0 + tx] = __float2bfloat16(tbuf[tx][ty * 4 + i]);
    }
}

// ---------------- conv5 direct part: MFMA implicit GEMM, tap-fused, pipelined ---
__global__ __launch_bounds__(256) void k_conv5_mfma(const hbf* __restrict__ wt,
                                                    const hbf* __restrict__ xtp,
                                                    float* __restrict__ c5acc) {
    __shared__ hbf As[2][3][128 * 32];   // 2 x 24KB
    __shared__ hbf Bs[2][136 * 32];      // 2 x 8.5KB
    const int tid = threadIdx.x;
    const int l = tid & 63, w = tid >> 6;
    const int m0 = blockIdx.x * 128;
    const int P0 = blockIdx.y * 128;
    const int g  = blockIdx.z;               // tap row (dy = g-1)
    const int n_img = P0 / 2304;
    const int pbase = P0 - n_img * 2304;
    const int r0 = tid >> 2;
    const int swzk = ((tid & 3) ^ ((r0 >> 1) & 3)) * 8;

    const int pp0 = pbase + 2 * (pbase / 48) + 51;
    const ptrdiff_t browbase = (ptrdiff_t)n_img * 2500 + pp0 + (g - 1) * 50 - 1;

    const int wm = (w & 1) * 64, wn = (w >> 1) * 64;
    int jb[4];
#pragma unroll
    for (int tj = 0; tj < 4; ++tj) {
        int p = pbase + wn + tj * 16 + (l & 15);
        jb[tj] = p + 2 * (p / 48) + 51 - pp0;          // 0..133
    }
    const int slotA = ((l >> 4) ^ ((l >> 1) & 3)) * 8;

    f32x4 acc[4][4];
#pragma unroll
    for (int i = 0; i < 4; ++i)
#pragma unroll
        for (int j = 0; j < 4; ++j) acc[i][j] = {0.f, 0.f, 0.f, 0.f};

    const hbf* gA = wt + ((size_t)(g * 1536 + m0 + r0)) * 2048 + swzk;
    const hbf* gB = xtp + (size_t)(browbase + r0) * 2048 + swzk;

#define STAGE5(buf, k0) do {                                                       \
        hbf* ldsA_ = &As[buf][0][0] + w * 512;                                     \
        hbf* ldsB_ = &Bs[buf][0] + w * 512;                                        \
        _Pragma("unroll")                                                          \
        for (int t_ = 0; t_ < 3; ++t_) {                                           \
            GLDS(gA + (size_t)t_ * 512 * 2048 + (k0),             ldsA_ + t_ * 4096);      \
            GLDS(gA + (size_t)t_ * 512 * 2048 + 64 * 2048 + (k0), ldsA_ + t_ * 4096 + 2048); \
        }                                                                          \
        GLDS(gB + (k0),                      ldsB_);                               \
        GLDS(gB + (size_t)64 * 2048 + (k0),  ldsB_ + 2048);                        \
        if (tid < 32)                                                              \
            GLDS(gB + (size_t)128 * 2048 + (k0), &Bs[buf][0] + 4096);              \
    } while (0)

    STAGE5(0, 0);
    int cur = 0;
#pragma unroll 2
    for (int k0 = 0; k0 < 2048; k0 += 32) {
        __syncthreads();   // drains prev stage (issued one compute phase ago)
        if (k0 + 32 < 2048) STAGE5(cur ^ 1, k0 + 32);
#pragma unroll
        for (int t = 0; t < 3; ++t) {
            bf16x8 af[4], bfr[4];
#pragma unroll
            for (int ti = 0; ti < 4; ++ti)
                af[ti] = *(const bf16x8*)(&As[cur][t][(wm + ti * 16 + (l & 15)) * 32 + slotA]);
#pragma unroll
            for (int tj = 0; tj < 4; ++tj) {
                const int brow = jb[tj] + t;
                bfr[tj] = *(const bf16x8*)(&Bs[cur][0] + brow * 32 + (((l >> 4) ^ ((brow >> 1) & 3)) * 8));
            }
#pragma unroll
            for (int ti = 0; ti < 4; ++ti)
#pragma unroll
                for (int tj = 0; tj < 4; ++tj)
                    acc[ti][tj] = __builtin_amdgcn_mfma_f32_16x16x32_bf16(
                        af[ti], bfr[tj], acc[ti][tj], 0, 0, 0);
        }
        cur ^= 1;
    }
#undef STAGE5

#pragma unroll
    for (int ti = 0; ti < 4; ++ti) {
        const int mrow = wm + ti * 16 + (l >> 4) * 4;
#pragma unroll
        for (int tj = 0; tj < 4; ++tj) {
            const int p = pbase + wn + tj * 16 + (l & 15);
            float* dst = c5acc + ((size_t)(n_img * 512 + m0 + mrow)) * 2304 + p;
#pragma unroll
            for (int r = 0; r < 4; ++r)
                atomicAdd(dst + (size_t)r * 2304, acc[ti][tj][r]);
        }
    }
}

// ---------------- epilogue: + psp(M)-part, BN, ReLU -> c5out bf16 ---------------
__global__ __launch_bounds__(256) void k_bnrelu_psp(const float* __restrict__ c5acc,
                                                    const float* __restrict__ M,
                                                    const float* __restrict__ bnp,
                                                    hbf* __restrict__ c5out) {
    const int co = blockIdx.x, n = blockIdx.y;
    __shared__ float Ms[450];
    const float* Mrow = M + ((size_t)(n * 512 + co)) * 450;
    for (int i = threadIdx.x; i < 450; i += 256) Ms[i] = Mrow[i];
    __syncthreads();
    float s, t; bn_coef(bnp, 512, co, s, t);
    const size_t base = ((size_t)(n * 512 + co)) * 2304;
#pragma unroll
    for (int i = 0; i < 9; ++i) {
        int p = threadIdx.x + i * 256;
        int y = p / 48, x = p % 48;
        float a = c5acc[base + p];
#pragma unroll
        for (int ky = 0; ky < 3; ++ky) {
            int yy = y + ky - 1;
            if (yy < 0 || yy > 47) continue;
#pragma unroll
            for (int kx = 0; kx < 3; ++kx) {
                int xx = x + kx - 1;
                if (xx < 0 || xx > 47) continue;
                const float* Mp = Ms + (ky * 3 + kx) * 50;
                float sa = Mp[0];
                B4 b2 = cell_interp(yy, xx, 2, 1);
                B4 b3 = cell_interp(yy, xx, 3, 5);
                B4 b6 = cell_interp(yy, xx, 6, 14);
                sa = fmaf(b2.w0, Mp[b2.c0], sa); sa = fmaf(b2.w1, Mp[b2.c1], sa);
                sa = fmaf(b2.w2, Mp[b2.c2], sa); sa = fmaf(b2.w3, Mp[b2.c3], sa);
                sa = fmaf(b3.w0, Mp[b3.c0], sa); sa = fmaf(b3.w1, Mp[b3.c1], sa);
                sa = fmaf(b3.w2, Mp[b3.c2], sa); sa = fmaf(b3.w3, Mp[b3.c3], sa);
                sa = fmaf(b6.w0, Mp[b6.c0], sa); sa = fmaf(b6.w1, Mp[b6.c1], sa);
                sa = fmaf(b6.w2, Mp[b6.c2], sa); sa = fmaf(b6.w3, Mp[b6.c3], sa);
                a += sa;
            }
        }
        c5out[base + p] = __float2bfloat16(fmaxf(fmaf(a, s, t), 0.f));
    }
}

// ---------------- conv6 at 48x48 (512->59, no bias), c5out bf16 -----------------
__global__ __launch_bounds__(192) void k_conv6s(const hbf* __restrict__ c5o,
                                                const float* __restrict__ w,
                                                float* __restrict__ out) {
    const int x = threadIdx.x;
    const int y = blockIdx.y * 4 + threadIdx.y;
    const int n = blockIdx.z;
    const int co = blockIdx.x;
    const int p = y * 48 + x;
    const hbf* ip = c5o + (size_t)n * 512 * 2304 + p;
    const float* wr = w + (size_t)co * 512;
    float a0 = 0.f, a1 = 0.f, a2 = 0.f, a3 = 0.f;
    for (int ci = 0; ci < 512; ci += 4) {
        a0 = fmaf(__bfloat162float(ip[(size_t)ci * 2304]),       wr[ci],     a0);
        a1 = fmaf(__bfloat162float(ip[(size_t)(ci + 1) * 2304]), wr[ci + 1], a1);
        a2 = fmaf(__bfloat162float(ip[(size_t)(ci + 2) * 2304]), wr[ci + 2], a2);
        a3 = fmaf(__bfloat162float(ip[(size_t)(ci + 3) * 2304]), wr[ci + 3], a3);
    }
    out[((size_t)n * 59 + co) * 2304 + p] = (a0 + a1) + (a2 + a3);
}

// ---------------- final: out = bias + sum_k att[k]*up96(c6s)[tap_k] -------------
__global__ void k_final(const float* __restrict__ att, const float* __restrict__ c6s,
                        const float* __restrict__ bias, float* __restrict__ out) {
    int idx = blockIdx.x * blockDim.x + threadIdx.x;  // 2*59*9216
    int p = idx % 9216;
    int nc = idx / 9216;
    int cls = nc % 59, n = nc / 59;
    int y = p / 96, x = p % 96;
    const float* ar = att + ((size_t)n * 9216 + p) * 9;
    const float* cp = c6s + (size_t)nc * 2304;
    int xs0[3], xs1[3], ys0[3], ys1[3];
    float fx[3], fy[3];
#pragma unroll
    for (int d = 0; d < 3; ++d) {
        int xx = x + 2 * d - 2;
        if (xx >= 0 && xx < 96) {
            int xn = xx * 47, x0 = xn / 95;
            xs0[d] = x0; xs1[d] = min(x0 + 1, 47);
            fx[d] = (float)(xn - x0 * 95) * (1.f / 95.f);
        } else { xs0[d] = -1; xs1[d] = 0; fx[d] = 0.f; }
        int yy = y + 2 * d - 2;
        if (yy >= 0 && yy < 96) {
            int yn = yy * 47, y0 = yn / 95;
            ys0[d] = y0; ys1[d] = min(y0 + 1, 47);
            fy[d] = (float)(yn - y0 * 95) * (1.f / 95.f);
        } else { ys0[d] = -1; ys1[d] = 0; fy[d] = 0.f; }
    }
    float a = bias[cls];
#pragma unroll
    for (int ky = 0; ky < 3; ++ky) {
        if (ys0[ky] < 0) continue;
        const float* r0 = cp + ys0[ky] * 48;
        const float* r1 = cp + ys1[ky] * 48;
        float wy = fy[ky];
#pragma unroll
        for (int kx = 0; kx < 3; ++kx) {
            if (xs0[kx] < 0) continue;
            float wx = fx[kx];
            float v0 = r0[xs0[kx]] * (1.f - wx) + r0[xs1[kx]] * wx;
            float v1 = r1[xs0[kx]] * (1.f - wx) + r1[xs1[kx]] * wx;
            a = fmaf(ar[ky * 3 + kx], v0 * (1.f - wy) + v1 * wy, a);
        }
    }
    out[idx] = a;
}

extern "C" void kernel_launch(void* const* d_in, const int* in_sizes, int n_in,
                              void* d_out, int out_size, void* d_ws, size_t ws_size,
                              hipStream_t stream) {
    const float* c1    = (const float*)d_in[0];
    const float* c2    = (const float*)d_in[1];
    const float* xin   = (const float*)d_in[2];
    const float* w_r1  = (const float*)d_in[3];
    const float* bn_r1 = (const float*)d_in[4];
    const float* w_r2  = (const float*)d_in[5];
    const float* bn_r2 = (const float*)d_in[6];
    const float* w_r3  = (const float*)d_in[7];
    const float* bn_r3 = (const float*)d_in[8];
    const float* w_p1  = (const float*)d_in[9];
    const float* bn_p1 = (const float*)d_in[10];
    const float* w_p2  = (const float*)d_in[11];
    const float* bn_p2 = (const float*)d_in[12];
    const float* w_p3  = (const float*)d_in[13];
    const float* bn_p3 = (const float*)d_in[14];
    const float* w_p4  = (const float*)d_in[15];
    const float* bn_p4 = (const float*)d_in[16];
    const float* w_c5  = (const float*)d_in[17];
    const float* bn_c5 = (const float*)d_in[18];
    const float* w_c6  = (const float*)d_in[19];
    const float* b_c6  = (const float*)d_in[20];
    float* out = (float*)d_out;
    (void)in_sizes; (void)n_in; (void)out_size; (void)ws_size;

    char* base = (char*)d_ws;
    float* att = (float*)base;                    // 663,552 B
    char*  A   = base + 663552;
    // ---- phase 1 layout (region A) ----
    // fill region [0, 13,979,648): c1t + r1t + c2acc (padding / atomic targets)
    hbf*   c1t   = (hbf*)A;                       // 10,240,000
    hbf*   r1t   = (hbf*)(A + 10240000);          //  2,560,000
    float* c2acc = (float*)(A + 12800000);        //  1,179,648  (fill ends 13,979,648)
    float* r1acc = (float*)(A + 13979648);        //  4,718,592  (plain stores)
    float* qacc  = (float*)(A + 18698240);        //  4,718,592  (plain stores, ends 23,416,832)
    float* q_t   = (float*)(A + 23416832);        //  4,718,592  px-major
    float* k_t   = (float*)(A + 28135424);        //  4,718,592  px-major (ends 32,854,016)
    hbf*   wr1t  = (hbf*)(A + 32854016);          //    294,912
    hbf*   wr2t  = (hbf*)(A + 33148928);          //     73,728  (ends 33,222,656)
    // ---- phase 2 early (region A): wpsp aliased under xtp, consumed pre-fill ----
    hbf*   wpsp   = (hbf*)A;                      // 18,874,368 (< xtp's 20,480,000)
    float* pooled = (float*)(A + 48791552);       //    819,200  ([n][50][2048])
    float* pconv  = (float*)(A + 49610752);       //    204,800
    float* M      = (float*)(A + 49815552);       //  1,843,200  (ends 51,658,752)
    // ---- phase 2 main (region A, reuses wpsp space) ----
    hbf*   xtp    = (hbf*)A;                      // 20,480,000
    float* c5acc  = (float*)(A + 20480000);       //  9,437,184
    hbf*   wt     = (hbf*)(A + 29917184);         // 18,874,368
    // ---- phase 2b (after conv5), aliased over xtp ----
    hbf*   c5out = (hbf*)A;                       //  4,718,592
    float* c6s   = (float*)(A + 4718592);         //  1,087,488
    // total ws: 663,552 + 51,658,752 = 52,322,304 B (unchanged)

    // ---- phase 1: attention branch ----
    k_fill0<<<dim3(13652), 256, 0, stream>>>((uint32_t*)A, 3494912);
    k_c1trans<<<dim3(288, 8, 2), dim3(32, 8), 0, stream>>>(c1, c1t);
    k_wsmall<<<dim3(80), 256, 0, stream>>>(w_r1, wr1t, w_r2, wr2t);
    k_dconv_mfma<256><<<dim3(288), 256, 0, stream>>>(wr1t, c1t, r1acc);
    k_ep_r1<<<dim3(288), 256, 0, stream>>>(r1acc, bn_r1, r1t);
    k_dconv_mfma<64><<<dim3(288), 256, 0, stream>>>(wr2t, r1t, qacc);
    k_qt<<<dim3(288, 2, 2), dim3(32, 8), 0, stream>>>(qacc, bn_r2, q_t);
    k_conv1x1_c2<<<dim3(4, 12, 8), dim3(48, 4), 0, stream>>>(c2, w_r3, c2acc);
    k_kt<<<dim3(288, 2, 2), dim3(32, 8), 0, stream>>>(c2acc, bn_r3, k_t);
    k_attention<<<dim3(288), 256, 0, stream>>>(q_t, k_t, att);
    // ---- phase 2: psp branch ----
    k_pool<<<dim3(4096), 64, 0, stream>>>(xin, pooled);
    k_pconv2<<<dim3(512, 2), 64, 0, stream>>>(pooled, w_p1, bn_p1, w_p2, bn_p2,
                                              w_p3, bn_p3, w_p4, bn_p4, pconv);
    k_wtrans_all<<<dim3(4352), 256, 0, stream>>>(w_c5, wt, wpsp);
    k_computeM2<<<dim3(8, 9, 14), 64, 0, stream>>>(wpsp, pconv, M);
    k_fill0<<<dim3(29216), 256, 0, stream>>>((uint32_t*)xtp, 7479296);
    k_xtrans<<<dim3(72, 64, 2), dim3(32, 8), 0, stream>>>(xin, xtp);
    k_conv5_mfma<<<dim3(4, 36, 3), 256, 0, stream>>>(wt, xtp, c5acc);
    k_bnrelu_psp<<<dim3(512, 2), 256, 0, stream>>>(c5acc, M, bn_c5, c5out);
    // classifier (conv6 commuted before upsample) + attention aggregation
    k_conv6s<<<dim3(59, 12, 2), dim3(48, 4), 0, stream>>>(c5out, w_c6, c6s);
    k_final<<<dim3(2 * 59 * 9216 / 256), 256, 0, stream>>>(att, c6s, b_c6, out);
}

// Round 8
// 642.734 us; speedup vs baseline: 1.0650x; 1.0164x over previous
//
#include <hip/hip_runtime.h>
#include <hip/hip_bf16.h>
#include <cstddef>
#include <cstdint>

typedef __hip_bfloat16 hbf;
typedef __bf16 bf16x8 __attribute__((ext_vector_type(8)));
typedef float f32x4 __attribute__((ext_vector_type(4)));

#define GLDS(gp, lp) __builtin_amdgcn_global_load_lds( \
    (const __attribute__((address_space(1))) void*)(gp), \
    (__attribute__((address_space(3))) void*)(lp), 16, 0, 0)

// bn: y = x*s + t, s = g*rsqrt(v+eps), t = b - m*s
__device__ __forceinline__ void bn_coef(const float* __restrict__ p, int C, int c,
                                        float& s, float& t) {
    float g = p[c];
    float b = p[C + c];
    float m = p[2 * C + c];
    float v = p[3 * C + c];
    s = g * rsqrtf(v + 1e-5f);
    t = b - m * s;
}

// ---------------- zero-fill (dwords) --------------------------------------------
__global__ void k_fill0(uint32_t* __restrict__ p, int n) {
    int i = blockIdx.x * blockDim.x + threadIdx.x;
    if (i < n) p[i] = 0u;
}

// ---------------- init: zero-fill phase-1 region + both small weight transposes -
__global__ __launch_bounds__(256) void k_init(uint32_t* __restrict__ fillp, int nfill,
                                              const float* __restrict__ w1,
                                              hbf* __restrict__ wt1,
                                              const float* __restrict__ w2,
                                              hbf* __restrict__ wt2) {
    int b = blockIdx.x;
    if (b < 13652) {
        int i = b * 256 + threadIdx.x;
        if (i < nfill) fillp[i] = 0u;
    } else if (b < 13652 + 64) {     // w_r1: [64][256][3][3]
        int idx = (b - 13652) * 256 + threadIdx.x;
        int co = idx >> 8, ci = idx & 255;
        const float* s = w1 + ((size_t)(co * 256 + ci)) * 9;
#pragma unroll
        for (int tap = 0; tap < 9; ++tap)
            wt1[((size_t)(tap * 64 + co)) * 256 + ci] = __float2bfloat16(s[tap]);
    } else {                          // w_r2: [64][64][3][3]
        int idx = (b - 13652 - 64) * 256 + threadIdx.x;
        int co = idx >> 6, ci = idx & 63;
        const float* s = w2 + ((size_t)(co * 64 + ci)) * 9;
#pragma unroll
        for (int tap = 0; tap < 9; ++tap)
            wt2[((size_t)(tap * 64 + co)) * 64 + ci] = __float2bfloat16(s[tap]);
    }
}

// ---------------- c1 fp32 [2,256,96,96] -> c1t bf16 [n][100*100][256], pad=2 ----
__global__ __launch_bounds__(256) void k_c1trans(const float* __restrict__ x,
                                                 hbf* __restrict__ c1t) {
    __shared__ float tbuf[32][33];
    const int p0 = blockIdx.x * 32, c0 = blockIdx.y * 32, n = blockIdx.z;
    const int tx = threadIdx.x, ty = threadIdx.y;
#pragma unroll
    for (int i = 0; i < 4; ++i) {
        int ci = c0 + ty * 4 + i;
        tbuf[ty * 4 + i][tx] = x[((size_t)(n * 256 + ci)) * 9216 + p0 + tx];
    }
    __syncthreads();
#pragma unroll
    for (int i = 0; i < 4; ++i) {
        int p = p0 + ty * 4 + i;
        int pp = (p / 96 + 2) * 100 + (p % 96) + 2;
        c1t[((size_t)(n * 10000 + pp)) * 256 + c0 + tx] = __float2bfloat16(tbuf[tx][ty * 4 + i]);
    }
}

// ---------------- dilated 3x3 conv (d=2) MFMA, 9 taps/block, fused BN+ReLU ------
// OUT=0: write r1t bf16 padded px-major. OUT=1: write q_t fp32 px-major.
// Single writer -> no accumulator round-trip (saves 37.8MB each).
template <int CI, int OUT>
__global__ __launch_bounds__(256) void k_dconv_mfma(const hbf* __restrict__ wt,
                                                    const hbf* __restrict__ it,
                                                    const float* __restrict__ bnp,
                                                    void* __restrict__ outp) {
    constexpr int KS = CI / 32;
    __shared__ hbf As[2][3][64 * 32];   // per-tap weights [64 co][32 k]
    __shared__ hbf Bs[2][72 * 32];      // union of pixel rows (tap col-shifts -2,0,+2)
    const int tid = threadIdx.x;
    const int l = tid & 63, w = tid >> 6;
    const int P0 = blockIdx.x * 64;
    const int r0 = tid >> 2;
    const int swzk = ((tid & 3) ^ ((r0 >> 1) & 3)) * 8;

    const int n_i = P0 / 9216;
    const int pl0 = P0 - n_i * 9216;
    const int pp0 = (pl0 / 96 + 2) * 100 + (pl0 % 96) + 2;
    const ptrdiff_t bb0 = (ptrdiff_t)n_i * 10000 + pp0 - 202;  // + g*200 per tap row

    const int wn = w * 16;
    const int pl_lane = pl0 + wn + (l & 15);
    const int jb = ((pl_lane / 96 + 2) * 100 + (pl_lane % 96) + 2) - pp0;  // 0..67
    const int slotA = ((l >> 4) ^ ((l >> 1) & 3)) * 8;

    f32x4 acc[4];
#pragma unroll
    for (int i = 0; i < 4; ++i) acc[i] = {0.f, 0.f, 0.f, 0.f};

#define STAGE_D(buf, gg, k0) do {                                              \
        const hbf* gA_ = wt + ((size_t)((gg) * 192 + r0)) * CI + swzk;         \
        const hbf* gB_ = it + (size_t)(bb0 + (gg) * 200 + r0) * CI + swzk;     \
        hbf* ldsA_ = &As[buf][0][0] + w * 512;                                 \
        hbf* ldsB_ = &Bs[buf][0] + w * 512;                                    \
        _Pragma("unroll")                                                      \
        for (int t_ = 0; t_ < 3; ++t_)                                         \
            GLDS(gA_ + (size_t)t_ * 64 * CI + (k0), ldsA_ + t_ * 2048);        \
        GLDS(gB_ + (k0), ldsB_);                                               \
        if (tid < 32)                                                          \
            GLDS(gB_ + (size_t)64 * CI + (k0), &Bs[buf][0] + 2048);            \
    } while (0)

    STAGE_D(0, 0, 0);
    int cur = 0;
    for (int g = 0; g < 3; ++g) {
#pragma unroll
        for (int ks = 0; ks < KS; ++ks) {
            __syncthreads();   // drains prev stage (issued one compute phase ago)
            int ns = g * KS + ks + 1;
            if (ns < 3 * KS) STAGE_D(cur ^ 1, ns / KS, (ns % KS) * 32);
#pragma unroll
            for (int t = 0; t < 3; ++t) {
                const int brow = jb + 2 * t;
                bf16x8 bfr = *(const bf16x8*)(&Bs[cur][0] + brow * 32 + (((l >> 4) ^ ((brow >> 1) & 3)) * 8));
#pragma unroll
                for (int ti = 0; ti < 4; ++ti) {
                    bf16x8 af = *(const bf16x8*)(&As[cur][t][(ti * 16 + (l & 15)) * 32 + slotA]);
                    acc[ti] = __builtin_amdgcn_mfma_f32_16x16x32_bf16(af, bfr, acc[ti], 0, 0, 0);
                }
            }
            cur ^= 1;
        }
    }
#undef STAGE_D

    const int px = P0 + wn + (l & 15);
    const int n2 = px / 9216, pl2 = px % 9216;
    if (OUT == 0) {
        const int pp = (pl2 / 96 + 2) * 100 + (pl2 % 96) + 2;
        hbf* dst = (hbf*)outp + ((size_t)(n2 * 10000 + pp)) * 64;
#pragma unroll
        for (int ti = 0; ti < 4; ++ti) {
            const int mrow = ti * 16 + (l >> 4) * 4;
            union { uint2 u; hbf h[4]; } pk;
#pragma unroll
            for (int r = 0; r < 4; ++r) {
                float s, t; bn_coef(bnp, 64, mrow + r, s, t);
                pk.h[r] = __float2bfloat16(fmaxf(fmaf(acc[ti][r], s, t), 0.f));
            }
            *(uint2*)(dst + mrow) = pk.u;
        }
    } else {
        float* dst = (float*)outp + ((size_t)(n2 * 9216 + pl2)) * 64;
#pragma unroll
        for (int ti = 0; ti < 4; ++ti) {
            const int mrow = ti * 16 + (l >> 4) * 4;
            f32x4 v;
#pragma unroll
            for (int r = 0; r < 4; ++r) {
                float s, t; bn_coef(bnp, 64, mrow + r, s, t);
                v[r] = fmaxf(fmaf(acc[ti][r], s, t), 0.f);
            }
            *(f32x4*)(dst + mrow) = v;
        }
    }
}

// ---------------- kt: upsample48->96 + BN + ReLU -> k_t fp32 [n][9216][64] ------
__global__ __launch_bounds__(256) void k_kt(const float* __restrict__ c2acc,
                                            const float* __restrict__ bnp,
                                            float* __restrict__ kt) {
    __shared__ float tbuf[32][33];
    const int p0 = blockIdx.x * 32, c0 = blockIdx.y * 32, n = blockIdx.z;
    const int tx = threadIdx.x, ty = threadIdx.y;
    const int p = p0 + tx;
    const int y = p / 96, x = p % 96;
    int yn = y * 47, xn = x * 47;
    int y0 = yn / 95, x0 = xn / 95;
    float wy = (float)(yn - y0 * 95) * (1.f / 95.f);
    float wx = (float)(xn - x0 * 95) * (1.f / 95.f);
    int y1 = min(y0 + 1, 47), x1 = min(x0 + 1, 47);
#pragma unroll
    for (int i = 0; i < 4; ++i) {
        int c = c0 + ty * 4 + i;
        const float* sp = c2acc + ((size_t)(n * 64 + c)) * 2304;
        float v00 = sp[y0 * 48 + x0], v01 = sp[y0 * 48 + x1];
        float v10 = sp[y1 * 48 + x0], v11 = sp[y1 * 48 + x1];
        tbuf[ty * 4 + i][tx] = (v00 * (1.f - wx) + v01 * wx) * (1.f - wy)
                             + (v10 * (1.f - wx) + v11 * wx) * wy;
    }
    __syncthreads();
    float s, t; bn_coef(bnp, 64, c0 + tx, s, t);
#pragma unroll
    for (int i = 0; i < 4; ++i) {
        int pw = p0 + ty * 4 + i;
        kt[((size_t)(n * 9216 + pw)) * 64 + c0 + tx] =
            fmaxf(fmaf(tbuf[tx][ty * 4 + i], s, t), 0.f);
    }
}

// ---------------- 1x1 conv on c2 (512->64), 16 co/block, ci split 4-ways --------
__global__ __launch_bounds__(192) void k_conv1x1_c2(const float* __restrict__ c2,
                                                    const float* __restrict__ w,
                                                    float* __restrict__ outacc) {
    const int x = threadIdx.x;
    const int y = blockIdx.y * 4 + threadIdx.y;
    const int n = blockIdx.z >> 2;
    const int ci0 = (blockIdx.z & 3) * 128;
    const int cg = blockIdx.x;
    const int p = y * 48 + x;
    float acc[16];
#pragma unroll
    for (int j = 0; j < 16; ++j) acc[j] = 0.f;
    for (int ci = ci0; ci < ci0 + 128; ++ci) {
        float iv = c2[(size_t)(n * 512 + ci) * 2304 + p];
#pragma unroll
        for (int j = 0; j < 16; ++j)
            acc[j] = fmaf(iv, w[(size_t)(cg * 16 + j) * 512 + ci], acc[j]);
    }
#pragma unroll
    for (int j = 0; j < 16; ++j)
        atomicAdd(&outacc[(size_t)(n * 64 + cg * 16 + j) * 2304 + p], acc[j]);
}

// ---------------- energy + softmax -> att [n,9216,9], px-major q/k --------------
__global__ __launch_bounds__(256) void k_attention(const float* __restrict__ qt,
                                                   const float* __restrict__ kt,
                                                   float* __restrict__ att) {
    const int wv = threadIdx.x >> 6;        // channel quarter 0..3
    const int ln = threadIdx.x & 63;
    const int p_abs = blockIdx.x * 64 + ln; // 0..18431
    const int n = p_abs / 9216, p = p_abs % 9216;
    const int y = p / 96, x = p % 96;
    float qv[16];
    {
        const f32x4* qr = (const f32x4*)(qt + (size_t)p_abs * 64 + wv * 16);
#pragma unroll
        for (int j = 0; j < 4; ++j) {
            f32x4 v = qr[j];
            qv[4 * j + 0] = v[0]; qv[4 * j + 1] = v[1];
            qv[4 * j + 2] = v[2]; qv[4 * j + 3] = v[3];
        }
    }
    const float* kb = kt + (size_t)n * 9216 * 64 + wv * 16;
    float e[9];
#pragma unroll
    for (int ky = 0; ky < 3; ++ky)
#pragma unroll
        for (int kx = 0; kx < 3; ++kx) {
            int yy = y + 2 * ky - 2, xx = x + 2 * kx - 2;
            float s = 0.f;
            if (yy >= 0 && yy < 96 && xx >= 0 && xx < 96) {
                const f32x4* kr = (const f32x4*)(kb + (size_t)(yy * 96 + xx) * 64);
#pragma unroll
                for (int j = 0; j < 4; ++j) {
                    f32x4 kv = kr[j];
                    s = fmaf(qv[4 * j + 0], kv[0], s);
                    s = fmaf(qv[4 * j + 1], kv[1], s);
                    s = fmaf(qv[4 * j + 2], kv[2], s);
                    s = fmaf(qv[4 * j + 3], kv[3], s);
                }
            }
            e[ky * 3 + kx] = s;
        }
    __shared__ float pe[9][4][64];
#pragma unroll
    for (int k = 0; k < 9; ++k) pe[k][wv][ln] = e[k];
    __syncthreads();
    if (threadIdx.x < 64) {
        float ee[9];
#pragma unroll
        for (int k = 0; k < 9; ++k)
            ee[k] = (pe[k][0][ln] + pe[k][1][ln]) + (pe[k][2][ln] + pe[k][3][ln]);
        float m = ee[0];
#pragma unroll
        for (int k = 1; k < 9; ++k) m = fmaxf(m, ee[k]);
        float sum = 0.f;
#pragma unroll
        for (int k = 0; k < 9; ++k) { ee[k] = __expf(ee[k] - m); sum += ee[k]; }
        float inv = 1.f / sum;
        float* ap = att + (size_t)p_abs * 9;
#pragma unroll
        for (int k = 0; k < 9; ++k) ap[k] = ee[k] * inv;
    }
}

// ---------------- adaptive avg pools s=1,2,3,6 -> pooled_t [n,50,2048] ----------
__global__ __launch_bounds__(64) void k_pool(const float* __restrict__ xin,
                                             float* __restrict__ pooled) {
    int b = blockIdx.x;            // n*2048+c
    int t = threadIdx.x;
    __shared__ float cells[50];
    if (t < 50) cells[t] = 0.f;
    __syncthreads();
    float rs = 0.f;
    if (t < 48) {
        const f32x4* rowv = (const f32x4*)(xin + (size_t)b * 2304 + t * 48);
        float s6[6];
#pragma unroll
        for (int j = 0; j < 6; ++j) {
            f32x4 u = rowv[2 * j], v = rowv[2 * j + 1];
            s6[j] = ((u[0] + u[1]) + (u[2] + u[3])) + ((v[0] + v[1]) + (v[2] + v[3]));
        }
        float s3a = s6[0] + s6[1], s3b = s6[2] + s6[3], s3c = s6[4] + s6[5];
        float s2a = s3a + s6[2], s2b = s6[3] + s3c;
        rs = s2a + s2b;
        int r6 = t >> 3, r3 = t >> 4, r2 = t / 24;
        atomicAdd(&cells[14 + r6 * 6 + 0], s6[0]);
        atomicAdd(&cells[14 + r6 * 6 + 1], s6[1]);
        atomicAdd(&cells[14 + r6 * 6 + 2], s6[2]);
        atomicAdd(&cells[14 + r6 * 6 + 3], s6[3]);
        atomicAdd(&cells[14 + r6 * 6 + 4], s6[4]);
        atomicAdd(&cells[14 + r6 * 6 + 5], s6[5]);
        atomicAdd(&cells[5 + r3 * 3 + 0], s3a);
        atomicAdd(&cells[5 + r3 * 3 + 1], s3b);
        atomicAdd(&cells[5 + r3 * 3 + 2], s3c);
        atomicAdd(&cells[1 + r2 * 2 + 0], s2a);
        atomicAdd(&cells[1 + r2 * 2 + 1], s2b);
    }
#pragma unroll
    for (int off = 32; off > 0; off >>= 1) rs += __shfl_down(rs, off);
    if (t == 0) atomicAdd(&cells[0], rs);
    __syncthreads();
    if (t < 50) {
        float inv = (t == 0) ? (1.f / 2304.f)
                  : (t < 5)  ? (1.f / 576.f)
                  : (t < 14) ? (1.f / 256.f)
                             : (1.f / 64.f);
        pooled[((size_t)(b >> 11) * 50 + t) * 2048 + (b & 2047)] = cells[t] * inv;
    }
}

// ---------------- pconv2: 1x1 conv 2048->512 per cell + BN + ReLU ---------------
__global__ __launch_bounds__(64) void k_pconv2(const float* __restrict__ pooled_t,
        const float* __restrict__ wp1, const float* __restrict__ bn1,
        const float* __restrict__ wp2, const float* __restrict__ bn2,
        const float* __restrict__ wp3, const float* __restrict__ bn3,
        const float* __restrict__ wp4, const float* __restrict__ bn4,
        float* __restrict__ pconv) {
    const int co = blockIdx.x, n = blockIdx.y;
    const int t = threadIdx.x;
    const int cell = (t < 50) ? t : 49;
    const float* w; const float* bnp;
    if (cell == 0)      { w = wp1; bnp = bn1; }
    else if (cell < 5)  { w = wp2; bnp = bn2; }
    else if (cell < 14) { w = wp3; bnp = bn3; }
    else                { w = wp4; bnp = bn4; }
    const float* pin = pooled_t + ((size_t)n * 50 + cell) * 2048;
    const float* wr = w + (size_t)co * 2048;
    float a0 = 0.f, a1 = 0.f, a2 = 0.f, a3 = 0.f;
    for (int c = 0; c < 2048; c += 4) {
        f32x4 v = *(const f32x4*)(pin + c);
        f32x4 ww = *(const f32x4*)(wr + c);
        a0 = fmaf(v[0], ww[0], a0);
        a1 = fmaf(v[1], ww[1], a1);
        a2 = fmaf(v[2], ww[2], a2);
        a3 = fmaf(v[3], ww[3], a3);
    }
    float a = (a0 + a1) + (a2 + a3);
    float s, tt; bn_coef(bnp, 512, co, s, tt);
    if (t < 50)
        pconv[((size_t)n * 512 + co) * 50 + cell] = fmaxf(fmaf(a, s, tt), 0.f);
}

// ---------------- w_c5 -> wt (ci<2048) AND wpsp (ci>=2048), one launch ----------
__global__ __launch_bounds__(256) void k_wtrans_all(const float* __restrict__ w5,
                                                    hbf* __restrict__ wt,
                                                    hbf* __restrict__ wpsp) {
    int b = blockIdx.x;
    if (b < 4096) {       // wt: [tap][512 co][2048 ci]
        int idx = b * 256 + threadIdx.x;   // 512*2048
        int co = idx >> 11, ci = idx & 2047;
        const float* s = w5 + ((size_t)co * 4096 + ci) * 9;
#pragma unroll
        for (int tap = 0; tap < 9; ++tap)
            wt[((size_t)(tap * 512 + co)) * 2048 + ci] = __float2bfloat16(s[tap]);
    } else {              // wpsp: [tap][4 b][512 c][512 co]
        int r = b - 4096;                   // 0..255, decode (x=8, y=4, z=8)
        const int co = (r & 7) * 64 + (threadIdx.x & 63);
        const int bb = (r >> 3) & 3;
        const int c0 = (r >> 5) * 64 + (threadIdx.x >> 6) * 16;
        for (int i = 0; i < 16; ++i) {
            int c = c0 + i;
            const float* s = w5 + ((size_t)co * 4096 + 2048 + bb * 512 + c) * 9;
#pragma unroll
            for (int tap = 0; tap < 9; ++tap)
                wpsp[(((size_t)(tap * 4 + bb) * 512) + c) * 512 + co] = __float2bfloat16(s[tap]);
        }
    }
}

// ---------------- computeM2: M[n,co,tap,cell] via coalesced bf16 weights --------
__global__ __launch_bounds__(64) void k_computeM2(const hbf* __restrict__ wpsp,
                                                  const float* __restrict__ pconv,
                                                  float* __restrict__ M) {
    const int cog = blockIdx.x, tap = blockIdx.y;
    const int n = blockIdx.z / 7, chunk = blockIdx.z % 7;
    const int cell0_t[7] = {0, 1, 5, 14, 23, 32, 41};
    const int ncell_t[7] = {1, 4, 9, 9, 9, 9, 9};
    const int btab[7]    = {0, 1, 2, 3, 3, 3, 3};
    const int cell0 = cell0_t[chunk], nc = ncell_t[chunk], b = btab[chunk];
    const int co = cog * 64 + threadIdx.x;
    const hbf* wb = wpsp + ((size_t)(tap * 4 + b) * 512) * 512 + co;
    const float* pc = pconv + (size_t)n * 512 * 50 + cell0;
    float acc[9];
#pragma unroll
    for (int j = 0; j < 9; ++j) acc[j] = 0.f;
    for (int c = 0; c < 512; ++c) {
        float w = __bfloat162float(wb[(size_t)c * 512]);
#pragma unroll
        for (int j = 0; j < 9; ++j)          // cells 0..8 past cell0 always in-bounds
            acc[j] = fmaf(w, pc[c * 50 + j], acc[j]);
    }
    float* Mp = M + ((size_t)(n * 512 + co) * 9 + tap) * 50 + cell0;
    for (int j = 0; j < nc; ++j) Mp[j] = acc[j];
}

// bilinear cell coefficients for branch with grid s x s at pixel (yy,xx) in 48x48
struct B4 { int c0, c1, c2, c3; float w0, w1, w2, w3; };
__device__ __forceinline__ B4 cell_interp(int yy, int xx, int s, int base) {
    int sm1 = s - 1;
    int yn = yy * sm1, xn = xx * sm1;
    int y0 = yn / 47, x0 = xn / 47;
    float wy = (float)(yn - y0 * 47) * (1.f / 47.f);
    float wx = (float)(xn - x0 * 47) * (1.f / 47.f);
    int y1 = min(y0 + 1, sm1), x1 = min(x0 + 1, sm1);
    B4 r;
    r.c0 = base + y0 * s + x0; r.c1 = base + y0 * s + x1;
    r.c2 = base + y1 * s + x0; r.c3 = base + y1 * s + x1;
    r.w0 = (1.f - wy) * (1.f - wx); r.w1 = (1.f - wy) * wx;
    r.w2 = wy * (1.f - wx);         r.w3 = wy * wx;
    return r;
}

// ---------------- x (fp32 [n,2048,48,48]) -> xtp (bf16 [n,50*50,2048], pad=0) ---
__global__ __launch_bounds__(256) void k_xtrans(const float* __restrict__ x,
                                                hbf* __restrict__ xtp) {
    __shared__ float tbuf[32][33];
    const int p0 = blockIdx.x * 32, c0 = blockIdx.y * 32, n = blockIdx.z;
    const int tx = threadIdx.x, ty = threadIdx.y;
#pragma unroll
    for (int i = 0; i < 4; ++i) {
        int ci = c0 + ty * 4 + i;
        tbuf[ty * 4 + i][tx] = x[((size_t)(n * 2048 + ci)) * 2304 + p0 + tx];
    }
    __syncthreads();
#pragma unroll
    for (int i = 0; i < 4; ++i) {
        int p = p0 + ty * 4 + i;
        int pp = (p / 48 + 1) * 50 + (p % 48) + 1;
        xtp[((size_t)(n * 2500 + pp)) * 2048 + c0 + tx] = __float2bfloat16(tbuf[tx][ty * 4 + i]);
    }
}

// ---------------- conv5 direct part: MFMA implicit GEMM, tap-fused, pipelined ---
__global__ __launch_bounds__(256) void k_conv5_mfma(const hbf* __restrict__ wt,
                                                    const hbf* __restrict__ xtp,
                                                    float* __restrict__ c5acc) {
    __shared__ hbf As[2][3][128 * 32];   // 2 x 24KB
    __shared__ hbf Bs[2][136 * 32];      // 2 x 8.5KB
    const int tid = threadIdx.x;
    const int l = tid & 63, w = tid >> 6;
    const int m0 = blockIdx.x * 128;
    const int P0 = blockIdx.y * 128;
    const int g  = blockIdx.z;               // tap row (dy = g-1)
    const int n_img = P0 / 2304;
    const int pbase = P0 - n_img * 2304;
    const int r0 = tid >> 2;
    const int swzk = ((tid & 3) ^ ((r0 >> 1) & 3)) * 8;

    const int pp0 = pbase + 2 * (pbase / 48) + 51;
    const ptrdiff_t browbase = (ptrdiff_t)n_img * 2500 + pp0 + (g - 1) * 50 - 1;

    const int wm = (w & 1) * 64, wn = (w >> 1) * 64;
    int jb[4];
#pragma unroll
    for (int tj = 0; tj < 4; ++tj) {
        int p = pbase + wn + tj * 16 + (l & 15);
        jb[tj] = p + 2 * (p / 48) + 51 - pp0;          // 0..133
    }
    const int slotA = ((l >> 4) ^ ((l >> 1) & 3)) * 8;

    f32x4 acc[4][4];
#pragma unroll
    for (int i = 0; i < 4; ++i)
#pragma unroll
        for (int j = 0; j < 4; ++j) acc[i][j] = {0.f, 0.f, 0.f, 0.f};

    const hbf* gA = wt + ((size_t)(g * 1536 + m0 + r0)) * 2048 + swzk;
    const hbf* gB = xtp + (size_t)(browbase + r0) * 2048 + swzk;

#define STAGE5(buf, k0) do {                                                       \
        hbf* ldsA_ = &As[buf][0][0] + w * 512;                                     \
        hbf* ldsB_ = &Bs[buf][0] + w * 512;                                        \
        _Pragma("unroll")                                                          \
        for (int t_ = 0; t_ < 3; ++t_) {                                           \
            GLDS(gA + (size_t)t_ * 512 * 2048 + (k0),             ldsA_ + t_ * 4096);      \
            GLDS(gA + (size_t)t_ * 512 * 2048 + 64 * 2048 + (k0), ldsA_ + t_ * 4096 + 2048); \
        }                                                                          \
        GLDS(gB + (k0),                      ldsB_);                               \
        GLDS(gB + (size_t)64 * 2048 + (k0),  ldsB_ + 2048);                        \
        if (tid < 32)                                                              \
            GLDS(gB + (size_t)128 * 2048 + (k0), &Bs[buf][0] + 4096);              \
    } while (0)

    STAGE5(0, 0);
    int cur = 0;
#pragma unroll 2
    for (int k0 = 0; k0 < 2048; k0 += 32) {
        __syncthreads();   // drains prev stage (issued one compute phase ago)
        if (k0 + 32 < 2048) STAGE5(cur ^ 1, k0 + 32);
#pragma unroll
        for (int t = 0; t < 3; ++t) {
            bf16x8 af[4], bfr[4];
#pragma unroll
            for (int ti = 0; ti < 4; ++ti)
                af[ti] = *(const bf16x8*)(&As[cur][t][(wm + ti * 16 + (l & 15)) * 32 + slotA]);
#pragma unroll
            for (int tj = 0; tj < 4; ++tj) {
                const int brow = jb[tj] + t;
                bfr[tj] = *(const bf16x8*)(&Bs[cur][0] + brow * 32 + (((l >> 4) ^ ((brow >> 1) & 3)) * 8));
            }
#pragma unroll
            for (int ti = 0; ti < 4; ++ti)
#pragma unroll
                for (int tj = 0; tj < 4; ++tj)
                    acc[ti][tj] = __builtin_amdgcn_mfma_f32_16x16x32_bf16(
                        af[ti], bfr[tj], acc[ti][tj], 0, 0, 0);
        }
        cur ^= 1;
    }
#undef STAGE5

#pragma unroll
    for (int ti = 0; ti < 4; ++ti) {
        const int mrow = wm + ti * 16 + (l >> 4) * 4;
#pragma unroll
        for (int tj = 0; tj < 4; ++tj) {
            const int p = pbase + wn + tj * 16 + (l & 15);
            float* dst = c5acc + ((size_t)(n_img * 512 + m0 + mrow)) * 2304 + p;
#pragma unroll
            for (int r = 0; r < 4; ++r)
                atomicAdd(dst + (size_t)r * 2304, acc[ti][tj][r]);
        }
    }
}

// ---------------- epilogue: + psp(M)-part, BN, ReLU -> c5out bf16 ---------------
__global__ __launch_bounds__(256) void k_bnrelu_psp(const float* __restrict__ c5acc,
                                                    const float* __restrict__ M,
                                                    const float* __restrict__ bnp,
                                                    hbf* __restrict__ c5out) {
    const int co = blockIdx.x, n = blockIdx.y;
    __shared__ float Ms[450];
    const float* Mrow = M + ((size_t)(n * 512 + co)) * 450;
    for (int i = threadIdx.x; i < 450; i += 256) Ms[i] = Mrow[i];
    __syncthreads();
    float s, t; bn_coef(bnp, 512, co, s, t);
    const size_t base = ((size_t)(n * 512 + co)) * 2304;
#pragma unroll
    for (int i = 0; i < 9; ++i) {
        int p = threadIdx.x + i * 256;
        int y = p / 48, x = p % 48;
        float a = c5acc[base + p];
#pragma unroll
        for (int ky = 0; ky < 3; ++ky) {
            int yy = y + ky - 1;
            if (yy < 0 || yy > 47) continue;
#pragma unroll
            for (int kx = 0; kx < 3; ++kx) {
                int xx = x + kx - 1;
                if (xx < 0 || xx > 47) continue;
                const float* Mp = Ms + (ky * 3 + kx) * 50;
                float sa = Mp[0];
                B4 b2 = cell_interp(yy, xx, 2, 1);
                B4 b3 = cell_interp(yy, xx, 3, 5);
                B4 b6 = cell_interp(yy, xx, 6, 14);
                sa = fmaf(b2.w0, Mp[b2.c0], sa); sa = fmaf(b2.w1, Mp[b2.c1], sa);
                sa = fmaf(b2.w2, Mp[b2.c2], sa); sa = fmaf(b2.w3, Mp[b2.c3], sa);
                sa = fmaf(b3.w0, Mp[b3.c0], sa); sa = fmaf(b3.w1, Mp[b3.c1], sa);
                sa = fmaf(b3.w2, Mp[b3.c2], sa); sa = fmaf(b3.w3, Mp[b3.c3], sa);
                sa = fmaf(b6.w0, Mp[b6.c0], sa); sa = fmaf(b6.w1, Mp[b6.c1], sa);
                sa = fmaf(b6.w2, Mp[b6.c2], sa); sa = fmaf(b6.w3, Mp[b6.c3], sa);
                a += sa;
            }
        }
        c5out[base + p] = __float2bfloat16(fmaxf(fmaf(a, s, t), 0.f));
    }
}

// ---------------- conv6 at 48x48 (512->59, no bias), c5out bf16 -----------------
__global__ __launch_bounds__(192) void k_conv6s(const hbf* __restrict__ c5o,
                                                const float* __restrict__ w,
                                                float* __restrict__ out) {
    const int x = threadIdx.x;
    const int y = blockIdx.y * 4 + threadIdx.y;
    const int n = blockIdx.z;
    const int co = blockIdx.x;
    const int p = y * 48 + x;
    const hbf* ip = c5o + (size_t)n * 512 * 2304 + p;
    const float* wr = w + (size_t)co * 512;
    float a0 = 0.f, a1 = 0.f, a2 = 0.f, a3 = 0.f;
    for (int ci = 0; ci < 512; ci += 4) {
        a0 = fmaf(__bfloat162float(ip[(size_t)ci * 2304]),       wr[ci],     a0);
        a1 = fmaf(__bfloat162float(ip[(size_t)(ci + 1) * 2304]), wr[ci + 1], a1);
        a2 = fmaf(__bfloat162float(ip[(size_t)(ci + 2) * 2304]), wr[ci + 2], a2);
        a3 = fmaf(__bfloat162float(ip[(size_t)(ci + 3) * 2304]), wr[ci + 3], a3);
    }
    out[((size_t)n * 59 + co) * 2304 + p] = (a0 + a1) + (a2 + a3);
}

// ---------------- final: out = bias + sum_k att[k]*up96(c6s)[tap_k] -------------
__global__ void k_final(const float* __restrict__ att, const float* __restrict__ c6s,
                        const float* __restrict__ bias, float* __restrict__ out) {
    int idx = blockIdx.x * blockDim.x + threadIdx.x;  // 2*59*9216
    int p = idx % 9216;
    int nc = idx / 9216;
    int cls = nc % 59, n = nc / 59;
    int y = p / 96, x = p % 96;
    const float* ar = att + ((size_t)n * 9216 + p) * 9;
    const float* cp = c6s + (size_t)nc * 2304;
    int xs0[3], xs1[3], ys0[3], ys1[3];
    float fx[3], fy[3];
#pragma unroll
    for (int d = 0; d < 3; ++d) {
        int xx = x + 2 * d - 2;
        if (xx >= 0 && xx < 96) {
            int xn = xx * 47, x0 = xn / 95;
            xs0[d] = x0; xs1[d] = min(x0 + 1, 47);
            fx[d] = (float)(xn - x0 * 95) * (1.f / 95.f);
        } else { xs0[d] = -1; xs1[d] = 0; fx[d] = 0.f; }
        int yy = y + 2 * d - 2;
        if (yy >= 0 && yy < 96) {
            int yn = yy * 47, y0 = yn / 95;
            ys0[d] = y0; ys1[d] = min(y0 + 1, 47);
            fy[d] = (float)(yn - y0 * 95) * (1.f / 95.f);
        } else { ys0[d] = -1; ys1[d] = 0; fy[d] = 0.f; }
    }
    float a = bias[cls];
#pragma unroll
    for (int ky = 0; ky < 3; ++ky) {
        if (ys0[ky] < 0) continue;
        const float* r0 = cp + ys0[ky] * 48;
        const float* r1 = cp + ys1[ky] * 48;
        float wy = fy[ky];
#pragma unroll
        for (int kx = 0; kx < 3; ++kx) {
            if (xs0[kx] < 0) continue;
            float wx = fx[kx];
            float v0 = r0[xs0[kx]] * (1.f - wx) + r0[xs1[kx]] * wx;
            float v1 = r1[xs0[kx]] * (1.f - wx) + r1[xs1[kx]] * wx;
            a = fmaf(ar[ky * 3 + kx], v0 * (1.f - wy) + v1 * wy, a);
        }
    }
    out[idx] = a;
}

extern "C" void kernel_launch(void* const* d_in, const int* in_sizes, int n_in,
                              void* d_out, int out_size, void* d_ws, size_t ws_size,
                              hipStream_t stream) {
    const float* c1    = (const float*)d_in[0];
    const float* c2    = (const float*)d_in[1];
    const float* xin   = (const float*)d_in[2];
    const float* w_r1  = (const float*)d_in[3];
    const float* bn_r1 = (const float*)d_in[4];
    const float* w_r2  = (const float*)d_in[5];
    const float* bn_r2 = (const float*)d_in[6];
    const float* w_r3  = (const float*)d_in[7];
    const float* bn_r3 = (const float*)d_in[8];
    const float* w_p1  = (const float*)d_in[9];
    const float* bn_p1 = (const float*)d_in[10];
    const float* w_p2  = (const float*)d_in[11];
    const float* bn_p2 = (const float*)d_in[12];
    const float* w_p3  = (const float*)d_in[13];
    const float* bn_p3 = (const float*)d_in[14];
    const float* w_p4  = (const float*)d_in[15];
    const float* bn_p4 = (const float*)d_in[16];
    const float* w_c5  = (const float*)d_in[17];
    const float* bn_c5 = (const float*)d_in[18];
    const float* w_c6  = (const float*)d_in[19];
    const float* b_c6  = (const float*)d_in[20];
    float* out = (float*)d_out;
    (void)in_sizes; (void)n_in; (void)out_size; (void)ws_size;

    char* base = (char*)d_ws;
    float* att = (float*)base;                    // 663,552 B
    char*  A   = base + 663552;
    // ---- phase 1 layout (region A) ----
    // fill region [0, 13,979,648): c1t + r1t + c2acc (padding / atomic targets)
    hbf*   c1t   = (hbf*)A;                       // 10,240,000
    hbf*   r1t   = (hbf*)(A + 10240000);          //  2,560,000
    float* c2acc = (float*)(A + 12800000);        //  1,179,648  (fill ends 13,979,648)
    float* q_t   = (float*)(A + 23416832);        //  4,718,592  px-major (direct from dconv2)
    float* k_t   = (float*)(A + 28135424);        //  4,718,592  px-major (ends 32,854,016)
    hbf*   wr1t  = (hbf*)(A + 32854016);          //    294,912
    hbf*   wr2t  = (hbf*)(A + 33148928);          //     73,728  (ends 33,222,656)
    // ---- phase 2 early (region A): wpsp aliased under xtp, consumed pre-fill ----
    hbf*   wpsp   = (hbf*)A;                      // 18,874,368 (< q_t's 23,416,832)
    float* pooled = (float*)(A + 48791552);       //    819,200  ([n][50][2048])
    float* pconv  = (float*)(A + 49610752);       //    204,800
    float* M      = (float*)(A + 49815552);       //  1,843,200  (ends 51,658,752)
    // ---- phase 2 main (region A, reuses wpsp space) ----
    hbf*   xtp    = (hbf*)A;                      // 20,480,000
    float* c5acc  = (float*)(A + 20480000);       //  9,437,184
    hbf*   wt     = (hbf*)(A + 29917184);         // 18,874,368
    // ---- phase 2b (after conv5), aliased over xtp ----
    hbf*   c5out = (hbf*)A;                       //  4,718,592
    float* c6s   = (float*)(A + 4718592);         //  1,087,488
    // total ws: 663,552 + 51,658,752 = 52,322,304 B (unchanged)

    // ---- phase 1: attention branch (7 dispatches, was 10) ----
    k_init<<<dim3(13732), 256, 0, stream>>>((uint32_t*)A, 3494912,
                                            w_r1, wr1t, w_r2, wr2t);
    k_c1trans<<<dim3(288, 8, 2), dim3(32, 8), 0, stream>>>(c1, c1t);
    k_dconv_mfma<256, 0><<<dim3(288), 256, 0, stream>>>(wr1t, c1t, bn_r1, r1t);
    k_dconv_mfma<64, 1><<<dim3(288), 256, 0, stream>>>(wr2t, r1t, bn_r2, q_t);
    k_conv1x1_c2<<<dim3(4, 12, 8), dim3(48, 4), 0, stream>>>(c2, w_r3, c2acc);
    k_kt<<<dim3(288, 2, 2), dim3(32, 8), 0, stream>>>(c2acc, bn_r3, k_t);
    k_attention<<<dim3(288), 256, 0, stream>>>(q_t, k_t, att);
    // ---- phase 2: psp branch ----
    k_pool<<<dim3(4096), 64, 0, stream>>>(xin, pooled);
    k_pconv2<<<dim3(512, 2), 64, 0, stream>>>(pooled, w_p1, bn_p1, w_p2, bn_p2,
                                              w_p3, bn_p3, w_p4, bn_p4, pconv);
    k_wtrans_all<<<dim3(4352), 256, 0, stream>>>(w_c5, wt, wpsp);
    k_computeM2<<<dim3(8, 9, 14), 64, 0, stream>>>(wpsp, pconv, M);
    k_fill0<<<dim3(29216), 256, 0, stream>>>((uint32_t*)xtp, 7479296);
    k_xtrans<<<dim3(72, 64, 2), dim3(32, 8), 0, stream>>>(xin, xtp);
    k_conv5_mfma<<<dim3(4, 36, 3), 256, 0, stream>>>(wt, xtp, c5acc);
    k_bnrelu_psp<<<dim3(512, 2), 256, 0, stream>>>(c5acc, M, bn_c5, c5out);
    // classifier (conv6 commuted before upsample) + attention aggregation
    k_conv6s<<<dim3(59, 12, 2), dim3(48, 4), 0, stream>>>(c5out, w_c6, c6s);
    k_final<<<dim3(2 * 59 * 9216 / 256), 256, 0, stream>>>(att, c6s, b_c6, out);
}